// Round 8
// baseline (265.933 us; speedup 1.0000x reference)
//
#include <hip/hip_runtime.h>

// Performer (FAVOR+) attention, MI355X.
// B=4 N=4096 H=16 D=64 DIM=1024 M=256.
// Pipeline:
//  k_wtrans:  W[k][n] f32 -> wt[g][n][k] fp16   (B^T layout for MFMA)
//  k_omconv:  omega f32 -> fp16
//  k_xconv:   x f32 -> xh fp16
//  k_gemm:    Q,K -> qkv (stride 2048, fp16); V -> vT bf16 in-epilogue.
//             256x256 tile, BK=64, 8-PHASE schedule (T3+T4). Readiness wait
//             {vmcnt(2); s_barrier} at TOP of P1/P5, BEFORE first ds_read of
//             the fresh buffer (r7 bug: wait was after the reads -> race/NaN).
//             vmcnt(2) leaves the 1 newer in-flight unit; last-iter P5 = 0.
//  k_kv:      pk = exp(k.om^T - |k|^2/2)/16 ; kv += pk^T v ; pksum
//  k_kvt:     kvt[bh][j][m] bf16: rows 0..63 = kv^T, row 64 = pksum, 65..79 = 0
//  k_out:     kvt staged in LDS once/block, omega in registers,
//             swapped proj mfma(om, q) -> pq^T b64 LDS writes, PV all-LDS.

typedef _Float16 half8 __attribute__((ext_vector_type(8)));
typedef short short8 __attribute__((ext_vector_type(8)));
typedef float f32x4 __attribute__((ext_vector_type(4)));
typedef unsigned short ushort4v __attribute__((ext_vector_type(4)));
typedef unsigned short ushort_t;
typedef unsigned int uint_t;

#define QKV_LD 2048

__device__ __forceinline__ ushort_t f2bf(float f) {
  uint_t u = __builtin_bit_cast(uint_t, f);
  u += 0x7fffu + ((u >> 16) & 1u);
  return (ushort_t)(u >> 16);
}

__device__ __forceinline__ void gload16(const void* g, void* l) {
  __builtin_amdgcn_global_load_lds(
      (const __attribute__((address_space(1))) void*)g,
      (__attribute__((address_space(3))) void*)l, 16, 0, 0);
}

// ---------------- W transpose+convert: wt[g][n][k] = (f16)W_g[k][n] ----------------
__global__ void k_wtrans(const float* __restrict__ Wq, const float* __restrict__ Wk,
                         const float* __restrict__ Wv, _Float16* __restrict__ wt) {
  __shared__ float t[32][33];
  const int g = blockIdx.z;
  const float* W = (g == 0) ? Wq : ((g == 1) ? Wk : Wv);
  const int n0 = blockIdx.x * 32, k0 = blockIdx.y * 32;
  const int tx = threadIdx.x, ty = threadIdx.y;
#pragma unroll
  for (int j = 0; j < 4; ++j)
    t[ty + j * 8][tx] = W[(size_t)(k0 + ty + j * 8) * 1024 + n0 + tx];
  __syncthreads();
  _Float16* o = wt + (size_t)g * 1024 * 1024;
#pragma unroll
  for (int j = 0; j < 4; ++j)
    o[(size_t)(n0 + ty + j * 8) * 1024 + k0 + tx] = (_Float16)t[tx][ty + j * 8];
}

__global__ void k_omconv(const float* __restrict__ omega, _Float16* __restrict__ om) {
  int i = blockIdx.x * 256 + threadIdx.x;
  if (i < 16384) om[i] = (_Float16)omega[i];
}

// ---------------- x convert: xh[n][k] = (f16)x[n][k] ----------------
__global__ __launch_bounds__(256) void k_xconv(const float* __restrict__ x,
                                               _Float16* __restrict__ xh) {
  size_t base = ((size_t)blockIdx.x * 256 + threadIdx.x) * 8;
  float4 f0 = *(const float4*)(x + base);
  float4 f1 = *(const float4*)(x + base + 4);
  half8 h;
  h[0] = (_Float16)f0.x; h[1] = (_Float16)f0.y; h[2] = (_Float16)f0.z; h[3] = (_Float16)f0.w;
  h[4] = (_Float16)f1.x; h[5] = (_Float16)f1.y; h[6] = (_Float16)f1.z; h[7] = (_Float16)f1.w;
  *(half8*)(xh + base) = h;
}

// ---------------- QKV GEMM: 256x256 tile, BK=64, 8-phase, 2-buf ----------------
// LDS layout per buf (A and B): 256 rows x 64 k f16, row pitch 128B.
//   slot swizzle: physical 16B-slot p stores logical k-block p ^ (row&7).
//   A rows use bit6<->7 swap so stage-unit S0 = {rows 0-63,128-191} is LDS rows
//   0-127 (contiguous 16KB); B units are plain row halves.
// Stage schedule per iter (buf0 = t(2i) computed P1-4, buf1 = t(2i+1) P5-8):
//   P1: t(2i+1)-Bh1  P2: t(2i+1)-AS0  P3: t(2i+1)-AS1  P4: t(2i+2)-Bh0
//   P5: t(2i+2)-Bh1  P6: t(2i+2)-AS0  P7: t(2i+2)-AS1  P8: t(2i+3)-Bh0
// Readiness: {vmcnt(2); barrier} at TOP of P1 (retires t(2i)'s 4 units) and
//   TOP of P5 (retires t(2i+1)); per-wave FIFO: 10 outstanding -> keep 2.
__global__ __launch_bounds__(512, 2) void k_gemm(const _Float16* __restrict__ xh,
                                                 const _Float16* __restrict__ wt,
                                                 ushort_t* __restrict__ qkv,
                                                 ushort_t* __restrict__ vT) {
  __shared__ _Float16 As[2][16384];  // 64 KB; T (36 KB) aliases As in epilogue
  __shared__ _Float16 Bs[2][16384];  // 64 KB
  const int vb = (blockIdx.x & 7) * 96 + (blockIdx.x >> 3);
  const int ct = vb % 12, rt = vb / 12;
  const int col0 = ct * 256, row0 = rt * 256;
  const int g = col0 >> 10;  // 0=Q 1=K 2=V
  const int col0g = col0 & 1023;
  const _Float16* wtg = wt + (size_t)g * (1024 * 1024);
  const int tid = threadIdx.x;
  const int lane = tid & 63;
  const int w = tid >> 6;
  const int wm = w >> 2, wn = w & 3;  // wave tile: rows [wm*128,+128), cols [wn*64,+64)
  const int l15 = lane & 15, l4 = lane >> 4;

  // stager coords: unit = 128 LDS rows x 8 slots; thread covers u = i*512+tid
  int urow[2], p8x[2], dstoff[2], abase[2];
#pragma unroll
  for (int i = 0; i < 2; ++i) {
    int u = i * 512 + tid;
    urow[i] = u >> 3;                                  // row within unit (0-127)
    p8x[i] = ((u & 7) ^ (urow[i] & 7)) * 8;            // swizzled source col (elems)
    dstoff[i] = u * 8;                                 // dst elems within unit
    abase[i] = (urow[i] & 63) | ((urow[i] & 64) << 1); // A actual-row base (S adds 64)
  }

  auto stageA = [&](int buf, int S, int kt) {
#pragma unroll
    for (int i = 0; i < 2; ++i)
      gload16(xh + (size_t)(row0 + abase[i] + S * 64) * 1024 + kt * 64 + p8x[i],
              &As[buf][S * 8192 + dstoff[i]]);
  };
  auto stageB = [&](int buf, int H, int kt) {
#pragma unroll
    for (int i = 0; i < 2; ++i)
      gload16(wtg + (size_t)(col0g + H * 128 + urow[i]) * 1024 + kt * 64 + p8x[i],
              &Bs[buf][H * 8192 + dstoff[i]]);
  };

  // reader swizzled slot offsets (elems) for k-halves 0/1
  const int aoff0 = ((l4) ^ (l15 & 7)) * 8;
  const int aoff1 = ((4 + l4) ^ (l15 & 7)) * 8;

  f32x4 acc[8][4] = {};

#define BARX asm volatile("s_barrier" ::: "memory")
#define VMC2 asm volatile("s_waitcnt vmcnt(2)" ::: "memory")
#define VMC0 asm volatile("s_waitcnt vmcnt(0)" ::: "memory")
#define PH_READS(bi, mh, ks, READB)                                          \
  {                                                                          \
    _Pragma("unroll") for (int q = 0; q < 4; ++q) {                          \
      int row = wm * 128 + (mh * 4 + q) * 16 + l15;                          \
      int pr = (row & 63) | ((row & 64) << 1) | ((row & 128) >> 1);          \
      av[q] = *(const half8*)&As[bi][pr * 64 + aoff##ks];                    \
    }                                                                        \
    if (READB) {                                                             \
      _Pragma("unroll") for (int q = 0; q < 4; ++q) {                        \
        int row = wn * 64 + q * 16 + l15;                                    \
        bv[q] = *(const half8*)&Bs[bi][row * 64 + aoff##ks];                 \
      }                                                                      \
    }                                                                        \
  }
#define PH_MFMA(mh)                                                          \
  {                                                                          \
    BARX;                                                                    \
    __builtin_amdgcn_s_setprio(1);                                           \
    _Pragma("unroll") for (int q = 0; q < 4; ++q)                            \
      _Pragma("unroll") for (int ni = 0; ni < 4; ++ni)                       \
        acc[mh * 4 + q][ni] = __builtin_amdgcn_mfma_f32_16x16x32_f16(        \
            av[q], bv[ni], acc[mh * 4 + q][ni], 0, 0, 0);                    \
    __builtin_amdgcn_s_setprio(0);                                           \
    BARX;                                                                    \
  }

  // prologue: t0 fully + t1-Bh0 (10 loads/wave)
  stageB(0, 0, 0); stageB(0, 1, 0); stageA(0, 0, 0); stageA(0, 1, 0);
  stageB(1, 0, 1);

#pragma unroll 1
  for (int i = 0; i < 8; ++i) {
    const int t1k = 2 * i + 1, nt0 = 2 * i + 2, nt1 = 2 * i + 3;
    half8 av[4], bv[4];
    // P1: buf0 (m0-3,k0) — buf0 tile t(2i) readiness FIRST, then reads
    VMC2; BARX;
    PH_READS(0, 0, 0, 1); stageB(1, 1, t1k); PH_MFMA(0);
    // P2: buf0 (m4-7,k0)
    PH_READS(0, 1, 0, 0); stageA(1, 0, t1k); PH_MFMA(1);
    // P3: buf0 (m0-3,k1)
    PH_READS(0, 0, 1, 1); stageA(1, 1, t1k); PH_MFMA(0);
    // P4: buf0 (m4-7,k1)
    PH_READS(0, 1, 1, 0); if (i < 7) stageB(0, 0, nt0); PH_MFMA(1);
    // P5: buf1 (m0-3,k0) — buf1 tile t(2i+1) readiness FIRST
    if (i < 7) { VMC2; } else { VMC0; }
    BARX;
    PH_READS(1, 0, 0, 1); if (i < 7) stageB(0, 1, nt0); PH_MFMA(0);
    // P6: buf1 (m4-7,k0)
    PH_READS(1, 1, 0, 0); if (i < 7) stageA(0, 0, nt0); PH_MFMA(1);
    // P7: buf1 (m0-3,k1)
    PH_READS(1, 0, 1, 1); if (i < 7) stageA(0, 1, nt0); PH_MFMA(0);
    // P8: buf1 (m4-7,k1)
    PH_READS(1, 1, 1, 0); if (i < 7) stageB(1, 0, nt1); PH_MFMA(1);
  }
#undef PH_READS
#undef PH_MFMA

  if (g < 2) {
    // Q/K epilogue: C row = (lane>>4)*4+reg, col = lane&15; fp16 bits
#pragma unroll
    for (int mi = 0; mi < 8; ++mi) {
      int gr0 = row0 + wm * 128 + mi * 16 + l4 * 4;
#pragma unroll
      for (int ni = 0; ni < 4; ++ni) {
        int gc = col0 + wn * 64 + ni * 16 + l15;
#pragma unroll
        for (int r = 0; r < 4; ++r)
          qkv[(size_t)(gr0 + r) * QKV_LD + gc] =
              __builtin_bit_cast(ushort_t, (_Float16)acc[mi][ni][r]);
      }
    }
  } else {
    // V epilogue: transpose 256n x 256c through LDS (aliasing As), write vT bf16.
    ushort_t(*T)[72] = reinterpret_cast<ushort_t(*)[72]>(&As[0][0]);
    const int b_ = row0 >> 12;    // batch
    const int n0_ = row0 & 4095;  // n base
#pragma unroll
    for (int p = 0; p < 4; ++p) {  // pass covers n in [p*64, p*64+64); FULL unroll
      __syncthreads();             // K-loop / prev-pass LDS reads complete
      if (wm == (p >> 1)) {
        const int mi0 = (p & 1) * 4;
#pragma unroll
        for (int mi4 = 0; mi4 < 4; ++mi4) {
#pragma unroll
          for (int ni = 0; ni < 4; ++ni) {
            int c = wn * 64 + ni * 16 + l15;
            ushort4v tv;
#pragma unroll
            for (int r = 0; r < 4; ++r) tv[r] = f2bf(acc[mi0 + mi4][ni][r]);
            *(ushort4v*)&T[c][mi4 * 16 + l4 * 4] = tv;
          }
        }
      }
      __syncthreads();
      // cooperative write: 256 c-rows x 64 n
#pragma unroll
      for (int i = 0; i < 4; ++i) {
        int u = i * 512 + tid;
        int c = u >> 3, nc = (u & 7) * 8;
        int h = (col0g + c) >> 6, d = c & 63;
        short8 v = *(const short8*)&T[c][nc];
        *(short8*)(vT + ((size_t)((b_ * 16 + h) * 64 + d)) * 4096 + n0_ + p * 64 + nc) = v;
      }
    }
  }
}

// ---------------- fused phi(k) + kv accumulation ----------------
__global__ __launch_bounds__(256) void k_kv(const ushort_t* __restrict__ qkv,
                                            const ushort_t* __restrict__ vT,
                                            const _Float16* __restrict__ om,
                                            float* __restrict__ kv,
                                            float* __restrict__ pksum) {
  __shared__ _Float16 kt[64][72];
  __shared__ ushort_t vt[64][72];
  __shared__ ushort_t pk[256][72];  // [m][n], rows 144B
  __shared__ float nrm[64];
  const int bh = blockIdx.x, split = blockIdx.y;
  const int b = bh >> 4, h = bh & 15;
  const int tid = threadIdx.x, lane = tid & 63, w = tid >> 6;
  const int l15 = lane & 15, l4 = lane >> 4;

  half8 bom[4][2];
#pragma unroll
  for (int mf = 0; mf < 4; ++mf)
#pragma unroll
    for (int ks = 0; ks < 2; ++ks)
      bom[mf][ks] = *(const half8*)(om + (size_t)(w * 64 + mf * 16 + l15) * 64 + ks * 32 + l4 * 8);

  f32x4 kvacc[4][4] = {};
  float psum[4] = {0.f, 0.f, 0.f, 0.f};

  for (int ch = 0; ch < 8; ++ch) {
    const int nbase = split * 512 + ch * 64;
#pragma unroll
    for (int i = 0; i < 2; ++i) {
      int c = i * 256 + tid;
      int r = c >> 3, s = c & 7;
      *(short8*)&kt[r][s * 8] =
          *(const short8*)(qkv + (size_t)(b * 4096 + nbase + r) * QKV_LD + 1024 + h * 64 + s * 8);
      *(short8*)&vt[r][s * 8] =
          *(const short8*)(vT + (size_t)(bh * 64 + r) * 4096 + nbase + s * 8);
    }
    __syncthreads();
    {
      int row = tid >> 2, part = tid & 3;
      float sm = 0.f;
#pragma unroll
      for (int i = 0; i < 16; ++i) {
        float kf = (float)kt[row][part * 16 + i];
        sm += kf * kf;
      }
      sm += __shfl_xor(sm, 1);
      sm += __shfl_xor(sm, 2);
      if ((tid & 3) == 0) nrm[row] = 0.5f * sm;
    }
    __syncthreads();
#pragma unroll
    for (int nf = 0; nf < 4; ++nf) {
      half8 a0 = *(const half8*)&kt[nf * 16 + l15][l4 * 8];
      half8 a1 = *(const half8*)&kt[nf * 16 + l15][32 + l4 * 8];
#pragma unroll
      for (int mf = 0; mf < 4; ++mf) {
        f32x4 f = {};
        f = __builtin_amdgcn_mfma_f32_16x16x32_f16(a0, bom[mf][0], f, 0, 0, 0);
        f = __builtin_amdgcn_mfma_f32_16x16x32_f16(a1, bom[mf][1], f, 0, 0, 0);
        ushort4v pw;
#pragma unroll
        for (int r = 0; r < 4; ++r) {
          int n = nf * 16 + l4 * 4 + r;
          float p = __expf(f[r] - nrm[n]) * 0.0625f;
          psum[mf] += p;
          pw[r] = f2bf(p);
        }
        *(ushort4v*)&pk[w * 64 + mf * 16 + l15][nf * 16 + l4 * 4] = pw;
      }
    }
    __syncthreads();
#pragma unroll
    for (int ks = 0; ks < 2; ++ks) {
      short8 pa[4];
#pragma unroll
      for (int mf = 0; mf < 4; ++mf)
        pa[mf] = *(const short8*)&pk[w * 64 + mf * 16 + l15][ks * 32 + l4 * 8];
#pragma unroll
      for (int df = 0; df < 4; ++df) {
        short8 bv = *(const short8*)&vt[df * 16 + l15][ks * 32 + l4 * 8];
#pragma unroll
        for (int mf = 0; mf < 4; ++mf)
          kvacc[mf][df] = __builtin_amdgcn_mfma_f32_16x16x32_bf16(pa[mf], bv, kvacc[mf][df], 0, 0, 0);
      }
    }
    __syncthreads();
  }
#pragma unroll
  for (int mf = 0; mf < 4; ++mf)
#pragma unroll
    for (int df = 0; df < 4; ++df)
#pragma unroll
      for (int r = 0; r < 4; ++r) {
        int m = w * 64 + mf * 16 + l4 * 4 + r;
        int d = df * 16 + l15;
        atomicAdd(&kv[((size_t)bh * 256 + m) * 64 + d], kvacc[mf][df][r]);
      }
#pragma unroll
  for (int mf = 0; mf < 4; ++mf) {
    float v = psum[mf];
    v += __shfl_xor(v, 16);
    v += __shfl_xor(v, 32);
    if (lane < 16) atomicAdd(&pksum[bh * 256 + w * 64 + mf * 16 + lane], v);
  }
}

// ---------------- kv -> kvt (B^T bf16, + pksum row 64, zero pad rows) ----------------
__global__ __launch_bounds__(256) void k_kvt(const float* __restrict__ kv,
                                             const float* __restrict__ pksum,
                                             ushort_t* __restrict__ kvt) {
  const int bh = blockIdx.x, tid = threadIdx.x;
  const int d = tid >> 2, mb = (tid & 3) * 64;
  for (int j = 0; j < 64; ++j) {
    int m = mb + j;
    kvt[((size_t)bh * 80 + d) * 256 + m] = f2bf(kv[((size_t)bh * 256 + m) * 64 + d]);
  }
  kvt[((size_t)bh * 80 + 64) * 256 + tid] = f2bf(pksum[bh * 256 + tid]);
  for (int r = 65; r < 80; ++r) kvt[((size_t)bh * 80 + r) * 256 + tid] = 0;
}

// ---------------- fused phi(q) + out (LDS-resident, reg-omega) ----------------
__global__ __launch_bounds__(512) void k_out(const ushort_t* __restrict__ qkv,
                                             const ushort_t* __restrict__ kvt,
                                             const _Float16* __restrict__ om,
                                             float* __restrict__ outp) {
  __shared__ ushort_t kvl[80][264];
  __shared__ _Float16 qt[128][72];
  __shared__ ushort_t pq[128][264];  // pq^T: [n][m]
  __shared__ float nrm[128];
  const int bh = blockIdx.x, ns = blockIdx.y;
  const int b = bh >> 4, h = bh & 15;
  const int tid = threadIdx.x, lane = tid & 63, w = tid >> 6;
  const int l15 = lane & 15, l4 = lane >> 4;
  const int wn = w >> 2, wm = w & 3;

#pragma unroll
  for (int i = 0; i < 5; ++i) {
    int u = i * 512 + tid;
    int r = u >> 5, c = (u & 31) * 8;
    *(short8*)&kvl[r][c] = *(const short8*)(kvt + ((size_t)bh * 80 + r) * 256 + c);
  }
  half8 bom[4][2];
#pragma unroll
  for (int mf = 0; mf < 4; ++mf)
#pragma unroll
    for (int ks = 0; ks < 2; ++ks)
      bom[mf][ks] = *(const half8*)(om + (size_t)(wm * 64 + mf * 16 + l15) * 64 + ks * 32 + l4 * 8);

  for (int ch = 0; ch < 4; ++ch) {
    const int n0 = ns * 512 + ch * 128;
#pragma unroll
    for (int i = 0; i < 2; ++i) {
      int u = i * 512 + tid;
      int r = u >> 3, s = (u & 7) * 8;
      *(half8*)&qt[r][s] =
          *(const half8*)((const _Float16*)qkv + (size_t)(b * 4096 + n0 + r) * QKV_LD + h * 64 + s);
    }
    __syncthreads();
    {
      int row = tid >> 2, part = tid & 3;
      float sm = 0.f;
#pragma unroll
      for (int i = 0; i < 16; ++i) {
        float qf = (float)qt[row][part * 16 + i];
        sm += qf * qf;
      }
      sm += __shfl_xor(sm, 1);
      sm += __shfl_xor(sm, 2);
      if ((tid & 3) == 0) nrm[row] = 0.5f * sm;
    }
    __syncthreads();
#pragma unroll
    for (int nf = 0; nf < 4; ++nf) {
      half8 qa0 = *(const half8*)&qt[wn * 64 + nf * 16 + l15][l4 * 8];
      half8 qa1 = *(const half8*)&qt[wn * 64 + nf * 16 + l15][32 + l4 * 8];
      float nr = nrm[wn * 64 + nf * 16 + l15];
#pragma unroll
      for (int mf = 0; mf < 4; ++mf) {
        f32x4 f = {};
        f = __builtin_amdgcn_mfma_f32_16x16x32_f16(bom[mf][0], qa0, f, 0, 0, 0);
        f = __builtin_amdgcn_mfma_f32_16x16x32_f16(bom[mf][1], qa1, f, 0, 0, 0);
        ushort4v pw;
#pragma unroll
        for (int r = 0; r < 4; ++r) {
          float p = __expf(f[r] - nr) * 0.0625f;
          pw[r] = f2bf(p);
        }
        *(ushort4v*)&pq[wn * 64 + nf * 16 + l15][wm * 64 + mf * 16 + l4 * 4] = pw;
      }
    }
    __syncthreads();
    f32x4 oacc[5] = {};
#pragma unroll
    for (int ks = 0; ks < 8; ++ks) {
      short8 pa = *(const short8*)&pq[w * 16 + l15][ks * 32 + l4 * 8];
#pragma unroll
      for (int cf = 0; cf < 5; ++cf) {
        short8 bv = *(const short8*)&kvl[cf * 16 + l15][ks * 32 + l4 * 8];
        oacc[cf] = __builtin_amdgcn_mfma_f32_16x16x32_bf16(pa, bv, oacc[cf], 0, 0, 0);
      }
    }
#pragma unroll
    for (int r = 0; r < 4; ++r) {
      float z = __shfl(oacc[4][r], lane & 48);
      float inv = 1.0f / (z + 1e-6f);
      int n = n0 + w * 16 + l4 * 4 + r;
#pragma unroll
      for (int cf = 0; cf < 4; ++cf)
        outp[(size_t)(b * 4096 + n) * 1024 + h * 64 + cf * 16 + l15] = oacc[cf][r] * inv;
    }
  }
}

extern "C" void kernel_launch(void* const* d_in, const int* in_sizes, int n_in,
                              void* d_out, int out_size, void* d_ws, size_t ws_size,
                              hipStream_t stream) {
  const float* x = (const float*)d_in[0];
  const float* Wq = (const float*)d_in[1];
  const float* Wk = (const float*)d_in[2];
  const float* Wv = (const float*)d_in[3];
  const float* omg = (const float*)d_in[4];
  float* outp = (float*)d_out;
  char* ws = (char*)d_ws;

  // ws layout (bytes), total 147,423,232 (~141 MB)
  _Float16* wt = (_Float16*)(ws);                 // 6,291,456
  _Float16* om = (_Float16*)(ws + 6291456);       //    32,768
  ushort_t* qkv = (ushort_t*)(ws + 6324224);      // 67,108,864 (Q|K, stride 2048)
  ushort_t* vT = (ushort_t*)(ws + 73433088);      // 33,554,432
  _Float16* xh = (_Float16*)(ws + 106987520);     // 33,554,432
  float* kv = (float*)(ws + 140541952);           // 4,194,304
  float* pksum = (float*)(ws + 144736256);        //    65,536
  ushort_t* kvt = (ushort_t*)(ws + 144801792);    // 2,621,440

  k_wtrans<<<dim3(32, 32, 3), dim3(32, 8), 0, stream>>>(Wq, Wk, Wv, wt);
  k_omconv<<<dim3(64), dim3(256), 0, stream>>>(omg, om);
  k_xconv<<<dim3(8192), dim3(256), 0, stream>>>(x, xh);
  k_gemm<<<dim3(768), dim3(512), 0, stream>>>(xh, wt, qkv, vT);
  hipMemsetAsync(kv, 0, 4194304 + 65536, stream);  // kv + pksum (contiguous)
  k_kv<<<dim3(64, 8), dim3(256), 0, stream>>>(qkv, vT, om, kv, pksum);
  k_kvt<<<dim3(64), dim3(256), 0, stream>>>(kv, pksum, kvt);
  k_out<<<dim3(64, 8), dim3(512), 0, stream>>>(qkv, kvt, om, outp);
}

// Round 10
// 253.958 us; speedup vs baseline: 1.0472x; 1.0472x over previous
//
#include <hip/hip_runtime.h>

// Performer (FAVOR+) attention, MI355X.
// B=4 N=4096 H=16 D=64 DIM=1024 M=256.
// Pipeline:
//  k_wtrans:  W[k][n] f32 -> wt[g][n][k] fp16   (B^T layout for MFMA)
//  k_omconv:  omega f32 -> fp16
//  k_xconv:   x f32 -> xh fp16
//  k_gemm:    Q,K -> qkv (stride 2048, fp16); V -> vT bf16 in-epilogue.
//             256x256 tile, BK=32, 2 phases/K-tile (T3+T4), 4-K-tile LDS ring
//             (16KB/operand/tile -> 128KB), 3-tile prefetch: stage A(t+3)@P1,
//             B(t+3)@P2. Entry vmcnt(8) keeps 8 loads (2 tiles) in flight.
//             r9 bug: BK=64 3-ring needs 192KB; buffers were half-sized ->
//             stage wrote into live ring buffers (absmax 5.4).
//  k_kv:      pk = exp(k.om^T - |k|^2/2)/16 ; kv += pk^T v ; pksum
//  k_kvt:     kvt[bh][j][m] bf16: rows 0..63 = kv^T, row 64 = pksum, 65..79 = 0
//  k_out:     kvt staged in LDS once/block, omega in registers,
//             swapped proj mfma(om, q) -> pq^T b64 LDS writes, PV all-LDS.

typedef _Float16 half8 __attribute__((ext_vector_type(8)));
typedef short short8 __attribute__((ext_vector_type(8)));
typedef float f32x4 __attribute__((ext_vector_type(4)));
typedef unsigned short ushort4v __attribute__((ext_vector_type(4)));
typedef unsigned short ushort_t;
typedef unsigned int uint_t;

#define QKV_LD 2048

__device__ __forceinline__ ushort_t f2bf(float f) {
  uint_t u = __builtin_bit_cast(uint_t, f);
  u += 0x7fffu + ((u >> 16) & 1u);
  return (ushort_t)(u >> 16);
}

__device__ __forceinline__ void gload16(const void* g, void* l) {
  __builtin_amdgcn_global_load_lds(
      (const __attribute__((address_space(1))) void*)g,
      (__attribute__((address_space(3))) void*)l, 16, 0, 0);
}

// ---------------- W transpose+convert: wt[g][n][k] = (f16)W_g[k][n] ----------------
__global__ void k_wtrans(const float* __restrict__ Wq, const float* __restrict__ Wk,
                         const float* __restrict__ Wv, _Float16* __restrict__ wt) {
  __shared__ float t[32][33];
  const int g = blockIdx.z;
  const float* W = (g == 0) ? Wq : ((g == 1) ? Wk : Wv);
  const int n0 = blockIdx.x * 32, k0 = blockIdx.y * 32;
  const int tx = threadIdx.x, ty = threadIdx.y;
#pragma unroll
  for (int j = 0; j < 4; ++j)
    t[ty + j * 8][tx] = W[(size_t)(k0 + ty + j * 8) * 1024 + n0 + tx];
  __syncthreads();
  _Float16* o = wt + (size_t)g * 1024 * 1024;
#pragma unroll
  for (int j = 0; j < 4; ++j)
    o[(size_t)(n0 + ty + j * 8) * 1024 + k0 + tx] = (_Float16)t[tx][ty + j * 8];
}

__global__ void k_omconv(const float* __restrict__ omega, _Float16* __restrict__ om) {
  int i = blockIdx.x * 256 + threadIdx.x;
  if (i < 16384) om[i] = (_Float16)omega[i];
}

// ---------------- x convert: xh[n][k] = (f16)x[n][k] ----------------
__global__ __launch_bounds__(256) void k_xconv(const float* __restrict__ x,
                                               _Float16* __restrict__ xh) {
  size_t base = ((size_t)blockIdx.x * 256 + threadIdx.x) * 8;
  float4 f0 = *(const float4*)(x + base);
  float4 f1 = *(const float4*)(x + base + 4);
  half8 h;
  h[0] = (_Float16)f0.x; h[1] = (_Float16)f0.y; h[2] = (_Float16)f0.z; h[3] = (_Float16)f0.w;
  h[4] = (_Float16)f1.x; h[5] = (_Float16)f1.y; h[6] = (_Float16)f1.z; h[7] = (_Float16)f1.w;
  *(half8*)(xh + base) = h;
}

// ---------------- QKV GEMM: 256x256 tile, BK=32, 2-phase/tile, 4-buf ring ----------------
// LDS per buf per operand: 256 rows x 32 k f16 (8192 elems = 16 KB), row 64B.
//   swizzle: phys 16B-slot = logical ^ ((row>>1)&3), both stage-source and read
//   (involution, rule #21). Residual 2-way (row vs row+8) is free (m136).
// Per tile t (buf=t&3):  entry {vmcnt; barrier};
//   P1: read A m0-3 + B (8x b128) | stage A(t+3) | {bar; setprio; 16 MFMA; bar}
//   P2: read A m4-7     (4x b128) | stage B(t+3) | {bar; setprio; 16 MFMA; bar}
// vmcnt: t<30 -> 8 (retire tile t, keep t+1,t+2); t==30 -> 4; t==31 -> 0.
__global__ __launch_bounds__(512, 2) void k_gemm(const _Float16* __restrict__ xh,
                                                 const _Float16* __restrict__ wt,
                                                 ushort_t* __restrict__ qkv,
                                                 ushort_t* __restrict__ vT) {
  __shared__ _Float16 As[4][8192];  // 64 KB; T (36 KB) aliases As in epilogue
  __shared__ _Float16 Bs[4][8192];  // 64 KB
  const int vb = (blockIdx.x & 7) * 96 + (blockIdx.x >> 3);
  const int ct = vb % 12, rt = vb / 12;
  const int col0 = ct * 256, row0 = rt * 256;
  const int g = col0 >> 10;  // 0=Q 1=K 2=V
  const int col0g = col0 & 1023;
  const _Float16* wtg = wt + (size_t)g * (1024 * 1024);
  const int tid = threadIdx.x;
  const int lane = tid & 63;
  const int w = tid >> 6;
  const int wm = w >> 2, wn = w & 3;  // wave tile: rows [wm*128,+128), cols [wn*64,+64)
  const int l15 = lane & 15, l4 = lane >> 4;

  // stager coords: tile-unit = 16 KB = 1024 chunks; thread covers u = i*512+tid
  int grow[2], scol[2], dst[2];
#pragma unroll
  for (int i = 0; i < 2; ++i) {
    int u = i * 512 + tid;
    int row = u >> 2, c = u & 3;
    grow[i] = row;
    scol[i] = (c ^ ((row >> 1) & 3)) * 8;  // pre-swizzled source col (elems)
    dst[i] = u * 8;                        // linear LDS dst (elems)
  }

  auto stageA = [&](int buf, int kt) {
#pragma unroll
    for (int i = 0; i < 2; ++i)
      gload16(xh + (size_t)(row0 + grow[i]) * 1024 + kt * 32 + scol[i], &As[buf][dst[i]]);
  };
  auto stageB = [&](int buf, int kt) {
#pragma unroll
    for (int i = 0; i < 2; ++i)
      gload16(wtg + (size_t)(col0g + grow[i]) * 1024 + kt * 32 + scol[i], &Bs[buf][dst[i]]);
  };

  f32x4 acc[8][4] = {};

#define BARX asm volatile("s_barrier" ::: "memory")
#define PH_READS(bi, mh, READB)                                              \
  {                                                                          \
    _Pragma("unroll") for (int q = 0; q < 4; ++q) {                          \
      int row = wm * 128 + (mh * 4 + q) * 16 + l15;                          \
      int sl = (l4 ^ ((row >> 1) & 3)) * 8;                                  \
      av[q] = *(const half8*)&As[bi][row * 32 + sl];                         \
    }                                                                        \
    if (READB) {                                                             \
      _Pragma("unroll") for (int q = 0; q < 4; ++q) {                        \
        int row = wn * 64 + q * 16 + l15;                                    \
        int sl = (l4 ^ ((row >> 1) & 3)) * 8;                                \
        bv[q] = *(const half8*)&Bs[bi][row * 32 + sl];                       \
      }                                                                      \
    }                                                                        \
  }
#define PH_MFMA(mh)                                                          \
  {                                                                          \
    BARX;                                                                    \
    __builtin_amdgcn_s_setprio(1);                                           \
    _Pragma("unroll") for (int q = 0; q < 4; ++q)                            \
      _Pragma("unroll") for (int ni = 0; ni < 4; ++ni)                       \
        acc[mh * 4 + q][ni] = __builtin_amdgcn_mfma_f32_16x16x32_f16(        \
            av[q], bv[ni], acc[mh * 4 + q][ni], 0, 0, 0);                    \
    __builtin_amdgcn_s_setprio(0);                                           \
    BARX;                                                                    \
  }

  // prologue: tiles 0,1,2 staged ({A,B} per tile -> 12 loads/thread)
  stageA(0, 0); stageB(0, 0);
  stageA(1, 1); stageB(1, 1);
  stageA(2, 2); stageB(2, 2);

#pragma unroll 1
  for (int t = 0; t < 32; ++t) {
    const int buf = t & 3, nb = (t + 3) & 3;
    const bool st = (t < 29);
    if (t < 30)       asm volatile("s_waitcnt vmcnt(8)" ::: "memory");
    else if (t == 30) asm volatile("s_waitcnt vmcnt(4)" ::: "memory");
    else              asm volatile("s_waitcnt vmcnt(0)" ::: "memory");
    BARX;
    half8 av[4], bv[4];
    // P1: (m0-3) + B reads | stage A(t+3)
    PH_READS(buf, 0, 1); if (st) stageA(nb, t + 3); PH_MFMA(0);
    // P2: (m4-7) reads (bv reused) | stage B(t+3)
    PH_READS(buf, 1, 0); if (st) stageB(nb, t + 3); PH_MFMA(1);
  }
#undef PH_READS
#undef PH_MFMA

  if (g < 2) {
    // Q/K epilogue: C row = (lane>>4)*4+reg, col = lane&15; fp16 bits
#pragma unroll
    for (int mi = 0; mi < 8; ++mi) {
      int gr0 = row0 + wm * 128 + mi * 16 + l4 * 4;
#pragma unroll
      for (int ni = 0; ni < 4; ++ni) {
        int gc = col0 + wn * 64 + ni * 16 + l15;
#pragma unroll
        for (int r = 0; r < 4; ++r)
          qkv[(size_t)(gr0 + r) * QKV_LD + gc] =
              __builtin_bit_cast(ushort_t, (_Float16)acc[mi][ni][r]);
      }
    }
  } else {
    // V epilogue: transpose 256n x 256c through LDS (aliasing As), write vT bf16.
    ushort_t(*T)[72] = reinterpret_cast<ushort_t(*)[72]>(&As[0][0]);
    const int b_ = row0 >> 12;    // batch
    const int n0_ = row0 & 4095;  // n base
#pragma unroll
    for (int p = 0; p < 4; ++p) {  // pass covers n in [p*64, p*64+64); FULL unroll
      __syncthreads();             // K-loop / prev-pass LDS reads complete
      if (wm == (p >> 1)) {
        const int mi0 = (p & 1) * 4;
#pragma unroll
        for (int mi4 = 0; mi4 < 4; ++mi4) {
#pragma unroll
          for (int ni = 0; ni < 4; ++ni) {
            int c = wn * 64 + ni * 16 + l15;
            ushort4v tv;
#pragma unroll
            for (int r = 0; r < 4; ++r) tv[r] = f2bf(acc[mi0 + mi4][ni][r]);
            *(ushort4v*)&T[c][mi4 * 16 + l4 * 4] = tv;
          }
        }
      }
      __syncthreads();
      // cooperative write: 256 c-rows x 64 n
#pragma unroll
      for (int i = 0; i < 4; ++i) {
        int u = i * 512 + tid;
        int c = u >> 3, nc = (u & 7) * 8;
        int h = (col0g + c) >> 6, d = c & 63;
        short8 v = *(const short8*)&T[c][nc];
        *(short8*)(vT + ((size_t)((b_ * 16 + h) * 64 + d)) * 4096 + n0_ + p * 64 + nc) = v;
      }
    }
  }
}

// ---------------- fused phi(k) + kv accumulation ----------------
__global__ __launch_bounds__(256) void k_kv(const ushort_t* __restrict__ qkv,
                                            const ushort_t* __restrict__ vT,
                                            const _Float16* __restrict__ om,
                                            float* __restrict__ kv,
                                            float* __restrict__ pksum) {
  __shared__ _Float16 kt[64][72];
  __shared__ ushort_t vt[64][72];
  __shared__ ushort_t pk[256][72];  // [m][n], rows 144B
  __shared__ float nrm[64];
  const int bh = blockIdx.x, split = blockIdx.y;
  const int b = bh >> 4, h = bh & 15;
  const int tid = threadIdx.x, lane = tid & 63, w = tid >> 6;
  const int l15 = lane & 15, l4 = lane >> 4;

  half8 bom[4][2];
#pragma unroll
  for (int mf = 0; mf < 4; ++mf)
#pragma unroll
    for (int ks = 0; ks < 2; ++ks)
      bom[mf][ks] = *(const half8*)(om + (size_t)(w * 64 + mf * 16 + l15) * 64 + ks * 32 + l4 * 8);

  f32x4 kvacc[4][4] = {};
  float psum[4] = {0.f, 0.f, 0.f, 0.f};

  for (int ch = 0; ch < 8; ++ch) {
    const int nbase = split * 512 + ch * 64;
#pragma unroll
    for (int i = 0; i < 2; ++i) {
      int c = i * 256 + tid;
      int r = c >> 3, s = c & 7;
      *(short8*)&kt[r][s * 8] =
          *(const short8*)(qkv + (size_t)(b * 4096 + nbase + r) * QKV_LD + 1024 + h * 64 + s * 8);
      *(short8*)&vt[r][s * 8] =
          *(const short8*)(vT + (size_t)(bh * 64 + r) * 4096 + nbase + s * 8);
    }
    __syncthreads();
    {
      int row = tid >> 2, part = tid & 3;
      float sm = 0.f;
#pragma unroll
      for (int i = 0; i < 16; ++i) {
        float kf = (float)kt[row][part * 16 + i];
        sm += kf * kf;
      }
      sm += __shfl_xor(sm, 1);
      sm += __shfl_xor(sm, 2);
      if ((tid & 3) == 0) nrm[row] = 0.5f * sm;
    }
    __syncthreads();
#pragma unroll
    for (int nf = 0; nf < 4; ++nf) {
      half8 a0 = *(const half8*)&kt[nf * 16 + l15][l4 * 8];
      half8 a1 = *(const half8*)&kt[nf * 16 + l15][32 + l4 * 8];
#pragma unroll
      for (int mf = 0; mf < 4; ++mf) {
        f32x4 f = {};
        f = __builtin_amdgcn_mfma_f32_16x16x32_f16(a0, bom[mf][0], f, 0, 0, 0);
        f = __builtin_amdgcn_mfma_f32_16x16x32_f16(a1, bom[mf][1], f, 0, 0, 0);
        ushort4v pw;
#pragma unroll
        for (int r = 0; r < 4; ++r) {
          int n = nf * 16 + l4 * 4 + r;
          float p = __expf(f[r] - nrm[n]) * 0.0625f;
          psum[mf] += p;
          pw[r] = f2bf(p);
        }
        *(ushort4v*)&pk[w * 64 + mf * 16 + l15][nf * 16 + l4 * 4] = pw;
      }
    }
    __syncthreads();
#pragma unroll
    for (int ks = 0; ks < 2; ++ks) {
      short8 pa[4];
#pragma unroll
      for (int mf = 0; mf < 4; ++mf)
        pa[mf] = *(const short8*)&pk[w * 64 + mf * 16 + l15][ks * 32 + l4 * 8];
#pragma unroll
      for (int df = 0; df < 4; ++df) {
        short8 bv = *(const short8*)&vt[df * 16 + l15][ks * 32 + l4 * 8];
#pragma unroll
        for (int mf = 0; mf < 4; ++mf)
          kvacc[mf][df] = __builtin_amdgcn_mfma_f32_16x16x32_bf16(pa[mf], bv, kvacc[mf][df], 0, 0, 0);
      }
    }
    __syncthreads();
  }
#pragma unroll
  for (int mf = 0; mf < 4; ++mf)
#pragma unroll
    for (int df = 0; df < 4; ++df)
#pragma unroll
      for (int r = 0; r < 4; ++r) {
        int m = w * 64 + mf * 16 + l4 * 4 + r;
        int d = df * 16 + l15;
        atomicAdd(&kv[((size_t)bh * 256 + m) * 64 + d], kvacc[mf][df][r]);
      }
#pragma unroll
  for (int mf = 0; mf < 4; ++mf) {
    float v = psum[mf];
    v += __shfl_xor(v, 16);
    v += __shfl_xor(v, 32);
    if (lane < 16) atomicAdd(&pksum[bh * 256 + w * 64 + mf * 16 + lane], v);
  }
}

// ---------------- kv -> kvt (B^T bf16, + pksum row 64, zero pad rows) ----------------
__global__ __launch_bounds__(256) void k_kvt(const float* __restrict__ kv,
                                             const float* __restrict__ pksum,
                                             ushort_t* __restrict__ kvt) {
  const int bh = blockIdx.x, tid = threadIdx.x;
  const int d = tid >> 2, mb = (tid & 3) * 64;
  for (int j = 0; j < 64; ++j) {
    int m = mb + j;
    kvt[((size_t)bh * 80 + d) * 256 + m] = f2bf(kv[((size_t)bh * 256 + m) * 64 + d]);
  }
  kvt[((size_t)bh * 80 + 64) * 256 + tid] = f2bf(pksum[bh * 256 + tid]);
  for (int r = 65; r < 80; ++r) kvt[((size_t)bh * 80 + r) * 256 + tid] = 0;
}

// ---------------- fused phi(q) + out (LDS-resident, reg-omega) ----------------
__global__ __launch_bounds__(512) void k_out(const ushort_t* __restrict__ qkv,
                                             const ushort_t* __restrict__ kvt,
                                             const _Float16* __restrict__ om,
                                             float* __restrict__ outp) {
  __shared__ ushort_t kvl[80][264];
  __shared__ _Float16 qt[128][72];
  __shared__ ushort_t pq[128][264];  // pq^T: [n][m]
  __shared__ float nrm[128];
  const int bh = blockIdx.x, ns = blockIdx.y;
  const int b = bh >> 4, h = bh & 15;
  const int tid = threadIdx.x, lane = tid & 63, w = tid >> 6;
  const int l15 = lane & 15, l4 = lane >> 4;
  const int wn = w >> 2, wm = w & 3;

#pragma unroll
  for (int i = 0; i < 5; ++i) {
    int u = i * 512 + tid;
    int r = u >> 5, c = (u & 31) * 8;
    *(short8*)&kvl[r][c] = *(const short8*)(kvt + ((size_t)bh * 80 + r) * 256 + c);
  }
  half8 bom[4][2];
#pragma unroll
  for (int mf = 0; mf < 4; ++mf)
#pragma unroll
    for (int ks = 0; ks < 2; ++ks)
      bom[mf][ks] = *(const half8*)(om + (size_t)(wm * 64 + mf * 16 + l15) * 64 + ks * 32 + l4 * 8);

  for (int ch = 0; ch < 4; ++ch) {
    const int n0 = ns * 512 + ch * 128;
#pragma unroll
    for (int i = 0; i < 2; ++i) {
      int u = i * 512 + tid;
      int r = u >> 3, s = (u & 7) * 8;
      *(half8*)&qt[r][s] =
          *(const half8*)((const _Float16*)qkv + (size_t)(b * 4096 + n0 + r) * QKV_LD + h * 64 + s);
    }
    __syncthreads();
    {
      int row = tid >> 2, part = tid & 3;
      float sm = 0.f;
#pragma unroll
      for (int i = 0; i < 16; ++i) {
        float qf = (float)qt[row][part * 16 + i];
        sm += qf * qf;
      }
      sm += __shfl_xor(sm, 1);
      sm += __shfl_xor(sm, 2);
      if ((tid & 3) == 0) nrm[row] = 0.5f * sm;
    }
    __syncthreads();
#pragma unroll
    for (int nf = 0; nf < 4; ++nf) {
      half8 qa0 = *(const half8*)&qt[wn * 64 + nf * 16 + l15][l4 * 8];
      half8 qa1 = *(const half8*)&qt[wn * 64 + nf * 16 + l15][32 + l4 * 8];
      float nr = nrm[wn * 64 + nf * 16 + l15];
#pragma unroll
      for (int mf = 0; mf < 4; ++mf) {
        f32x4 f = {};
        f = __builtin_amdgcn_mfma_f32_16x16x32_f16(bom[mf][0], qa0, f, 0, 0, 0);
        f = __builtin_amdgcn_mfma_f32_16x16x32_f16(bom[mf][1], qa1, f, 0, 0, 0);
        ushort4v pw;
#pragma unroll
        for (int r = 0; r < 4; ++r) {
          float p = __expf(f[r] - nr) * 0.0625f;
          pw[r] = f2bf(p);
        }
        *(ushort4v*)&pq[wn * 64 + nf * 16 + l15][wm * 64 + mf * 16 + l4 * 4] = pw;
      }
    }
    __syncthreads();
    f32x4 oacc[5] = {};
#pragma unroll
    for (int ks = 0; ks < 8; ++ks) {
      short8 pa = *(const short8*)&pq[w * 16 + l15][ks * 32 + l4 * 8];
#pragma unroll
      for (int cf = 0; cf < 5; ++cf) {
        short8 bv = *(const short8*)&kvl[cf * 16 + l15][ks * 32 + l4 * 8];
        oacc[cf] = __builtin_amdgcn_mfma_f32_16x16x32_bf16(pa, bv, oacc[cf], 0, 0, 0);
      }
    }
#pragma unroll
    for (int r = 0; r < 4; ++r) {
      float z = __shfl(oacc[4][r], lane & 48);
      float inv = 1.0f / (z + 1e-6f);
      int n = n0 + w * 16 + l4 * 4 + r;
#pragma unroll
      for (int cf = 0; cf < 4; ++cf)
        outp[(size_t)(b * 4096 + n) * 1024 + h * 64 + cf * 16 + l15] = oacc[cf][r] * inv;
    }
  }
}

extern "C" void kernel_launch(void* const* d_in, const int* in_sizes, int n_in,
                              void* d_out, int out_size, void* d_ws, size_t ws_size,
                              hipStream_t stream) {
  const float* x = (const float*)d_in[0];
  const float* Wq = (const float*)d_in[1];
  const float* Wk = (const float*)d_in[2];
  const float* Wv = (const float*)d_in[3];
  const float* omg = (const float*)d_in[4];
  float* outp = (float*)d_out;
  char* ws = (char*)d_ws;

  // ws layout (bytes), total 147,423,232 (~141 MB)
  _Float16* wt = (_Float16*)(ws);                 // 6,291,456
  _Float16* om = (_Float16*)(ws + 6291456);       //    32,768
  ushort_t* qkv = (ushort_t*)(ws + 6324224);      // 67,108,864 (Q|K, stride 2048)
  ushort_t* vT = (ushort_t*)(ws + 73433088);      // 33,554,432
  _Float16* xh = (_Float16*)(ws + 106987520);     // 33,554,432
  float* kv = (float*)(ws + 140541952);           // 4,194,304
  float* pksum = (float*)(ws + 144736256);        //    65,536
  ushort_t* kvt = (ushort_t*)(ws + 144801792);    // 2,621,440

  k_wtrans<<<dim3(32, 32, 3), dim3(32, 8), 0, stream>>>(Wq, Wk, Wv, wt);
  k_omconv<<<dim3(64), dim3(256), 0, stream>>>(omg, om);
  k_xconv<<<dim3(8192), dim3(256), 0, stream>>>(x, xh);
  k_gemm<<<dim3(768), dim3(512), 0, stream>>>(xh, wt, qkv, vT);
  hipMemsetAsync(kv, 0, 4194304 + 65536, stream);  // kv + pksum (contiguous)
  k_kv<<<dim3(64, 8), dim3(256), 0, stream>>>(qkv, vT, om, kv, pksum);
  k_kvt<<<dim3(64), dim3(256), 0, stream>>>(kv, pksum, kvt);
  k_out<<<dim3(64, 8), dim3(512), 0, stream>>>(qkv, kvt, om, outp);
}

// Round 11
// 243.819 us; speedup vs baseline: 1.0907x; 1.0416x over previous
//
#include <hip/hip_runtime.h>

// Performer (FAVOR+) attention, MI355X.
// B=4 N=4096 H=16 D=64 DIM=1024 M=256.
// Pipeline (6 launches):
//  k_wtrans:  W f32 -> wt[g][n][k] fp16 (B^T); z==3 slice converts omega->fp16
//  k_xconv:   x f32 -> xh fp16
//  k_gemm:    r6 structure (proven 111us/40%): 256x256, BK=32, ring-4 LDS,
//             counted vmcnt(6), 1 barrier/K-tile, setprio, XOR swizzle;
//             Q,K -> qkv fp16 (stride 2048); V -> vT bf16 in-epilogue.
//  memset kv/pksum
//  k_kv:      gload16-staged kt/vt (slot-XOR swizzle), 1-chunk prefetch,
//             entry-only vmcnt drain + lgkm-only mid-barriers, vectorized nrm;
//             pk = exp(k.om^T-|k|^2/2)/16; kv += pk^T v (atomic); pksum
//  k_out:     kv f32 transposed in-LDS (k_kvt folded in), kvl+pq resident,
//             gload16-staged q with prefetch; out = (pq@kv)/(pq@pksum+1e-6)

typedef _Float16 half8 __attribute__((ext_vector_type(8)));
typedef short short8 __attribute__((ext_vector_type(8)));
typedef float f32x4 __attribute__((ext_vector_type(4)));
typedef unsigned short ushort4v __attribute__((ext_vector_type(4)));
typedef unsigned short ushort_t;
typedef unsigned int uint_t;

#define QKV_LD 2048

__device__ __forceinline__ ushort_t f2bf(float f) {
  uint_t u = __builtin_bit_cast(uint_t, f);
  u += 0x7fffu + ((u >> 16) & 1u);
  return (ushort_t)(u >> 16);
}

__device__ __forceinline__ void gload16(const void* g, void* l) {
  __builtin_amdgcn_global_load_lds(
      (const __attribute__((address_space(1))) void*)g,
      (__attribute__((address_space(3))) void*)l, 16, 0, 0);
}

#define ENTRY_BAR                                                  \
  asm volatile("s_waitcnt vmcnt(0) lgkmcnt(0)" ::: "memory");      \
  asm volatile("s_barrier" ::: "memory")
#define MID_BAR                                                    \
  asm volatile("s_waitcnt lgkmcnt(0)" ::: "memory");               \
  asm volatile("s_barrier" ::: "memory")

// ---------------- W transpose+convert (+ omega convert on z==3) ----------------
__global__ void k_wtrans(const float* __restrict__ Wq, const float* __restrict__ Wk,
                         const float* __restrict__ Wv, const float* __restrict__ omega,
                         _Float16* __restrict__ wt, _Float16* __restrict__ om) {
  const int g = blockIdx.z;
  const int tx = threadIdx.x, ty = threadIdx.y;
  if (g == 3) {
    int idx = blockIdx.y * 32 + blockIdx.x;
    if (idx < 64) {
      int i = idx * 256 + ty * 32 + tx;
      om[i] = (_Float16)omega[i];
    }
    return;
  }
  __shared__ float t[32][33];
  const float* W = (g == 0) ? Wq : ((g == 1) ? Wk : Wv);
  const int n0 = blockIdx.x * 32, k0 = blockIdx.y * 32;
#pragma unroll
  for (int j = 0; j < 4; ++j)
    t[ty + j * 8][tx] = W[(size_t)(k0 + ty + j * 8) * 1024 + n0 + tx];
  __syncthreads();
  _Float16* o = wt + (size_t)g * 1024 * 1024;
#pragma unroll
  for (int j = 0; j < 4; ++j)
    o[(size_t)(n0 + ty + j * 8) * 1024 + k0 + tx] = (_Float16)t[tx][ty + j * 8];
}

// ---------------- x convert: xh[n][k] = (f16)x[n][k] ----------------
__global__ __launch_bounds__(256) void k_xconv(const float* __restrict__ x,
                                               _Float16* __restrict__ xh) {
  size_t base = ((size_t)blockIdx.x * 256 + threadIdx.x) * 8;
  float4 f0 = *(const float4*)(x + base);
  float4 f1 = *(const float4*)(x + base + 4);
  half8 h;
  h[0] = (_Float16)f0.x; h[1] = (_Float16)f0.y; h[2] = (_Float16)f0.z; h[3] = (_Float16)f0.w;
  h[4] = (_Float16)f1.x; h[5] = (_Float16)f1.y; h[6] = (_Float16)f1.z; h[7] = (_Float16)f1.w;
  *(half8*)(xh + base) = h;
}

// ---------------- QKV GEMM: r6 structure (256x256, BK=32, ring-4, 1 bar/K-tile) ----------------
__global__ __launch_bounds__(512, 2) void k_gemm(const _Float16* __restrict__ xh,
                                                 const _Float16* __restrict__ wt,
                                                 ushort_t* __restrict__ qkv,
                                                 ushort_t* __restrict__ vT) {
  __shared__ _Float16 As[4][8192];  // 64 KB; T (36 KB) aliases As in epilogue
  __shared__ _Float16 Bs[4][8192];  // 64 KB
  const int vb = (blockIdx.x & 7) * 96 + (blockIdx.x >> 3);
  const int ct = vb % 12, rt = vb / 12;
  const int col0 = ct * 256, row0 = rt * 256;
  const int g = col0 >> 10;  // 0=Q 1=K 2=V
  const int col0g = col0 & 1023;
  const _Float16* wtg = wt + (size_t)g * (1024 * 1024);
  const int tid = threadIdx.x;
  const int lane = tid & 63;
  const int w = tid >> 6;
  const int wm = w >> 2, wn = w & 3;
  const int l15 = lane & 15, l4 = lane >> 4;

  int srow[2], scol[2], dst[2];
#pragma unroll
  for (int i = 0; i < 2; ++i) {
    int u = i * 512 + tid;
    int rb = u >> 6, rr = (u >> 2) & 15, ccb = u & 3;
    srow[i] = rb * 16 + rr;
    scol[i] = (ccb * 8) ^ ((rr & 8) ? 16 : 0);
    dst[i] = u * 8;
  }
  const int kx = (l4 * 8) ^ ((l15 & 8) ? 16 : 0);

  auto stageA = [&](int b, int kt) {
#pragma unroll
    for (int i = 0; i < 2; ++i)
      gload16(xh + (size_t)(row0 + srow[i]) * 1024 + kt * 32 + scol[i], &As[b][dst[i]]);
  };
  auto stageB = [&](int b, int kt) {
#pragma unroll
    for (int i = 0; i < 2; ++i)
      gload16(wtg + (size_t)(col0g + srow[i]) * 1024 + kt * 32 + scol[i], &Bs[b][dst[i]]);
  };

  f32x4 acc[8][4] = {};

  stageA(0, 0); stageB(0, 0);
  stageA(1, 1); stageB(1, 1);

  for (int kt = 0; kt < 32; ++kt) {
    const int b = kt & 3, b2 = (kt + 2) & 3;
    if (kt < 30) stageA(b2, kt + 2);
    if (kt < 30)       asm volatile("s_waitcnt vmcnt(6)" ::: "memory");
    else if (kt == 30) asm volatile("s_waitcnt vmcnt(4)" ::: "memory");
    else               asm volatile("s_waitcnt vmcnt(0)" ::: "memory");
    asm volatile("s_barrier" ::: "memory");

    const _Float16* Ab = &As[b][0];
    const _Float16* Bb = &Bs[b][0];
    half8 av[4], bv[4];
#pragma unroll
    for (int mi = 0; mi < 4; ++mi)
      av[mi] = *(const half8*)&Ab[(wm * 8 + mi) * 512 + l15 * 32 + kx];
#pragma unroll
    for (int ni = 0; ni < 4; ++ni)
      bv[ni] = *(const half8*)&Bb[(wn * 4 + ni) * 512 + l15 * 32 + kx];
    if (kt < 30) stageB(b2, kt + 2);
    __builtin_amdgcn_s_setprio(1);
#pragma unroll
    for (int mi = 0; mi < 4; ++mi)
#pragma unroll
      for (int ni = 0; ni < 4; ++ni)
        acc[mi][ni] = __builtin_amdgcn_mfma_f32_16x16x32_f16(av[mi], bv[ni], acc[mi][ni], 0, 0, 0);
    __builtin_amdgcn_s_setprio(0);

    half8 av2[4];
#pragma unroll
    for (int mi = 0; mi < 4; ++mi)
      av2[mi] = *(const half8*)&Ab[(wm * 8 + 4 + mi) * 512 + l15 * 32 + kx];
    __builtin_amdgcn_s_setprio(1);
#pragma unroll
    for (int mi = 0; mi < 4; ++mi)
#pragma unroll
      for (int ni = 0; ni < 4; ++ni)
        acc[4 + mi][ni] = __builtin_amdgcn_mfma_f32_16x16x32_f16(av2[mi], bv[ni], acc[4 + mi][ni], 0, 0, 0);
    __builtin_amdgcn_s_setprio(0);
  }

  if (g < 2) {
#pragma unroll
    for (int mi = 0; mi < 8; ++mi) {
      int gr0 = row0 + wm * 128 + mi * 16 + l4 * 4;
#pragma unroll
      for (int ni = 0; ni < 4; ++ni) {
        int gc = col0 + wn * 64 + ni * 16 + l15;
#pragma unroll
        for (int r = 0; r < 4; ++r)
          qkv[(size_t)(gr0 + r) * QKV_LD + gc] =
              __builtin_bit_cast(ushort_t, (_Float16)acc[mi][ni][r]);
      }
    }
  } else {
    ushort_t(*T)[72] = reinterpret_cast<ushort_t(*)[72]>(&As[0][0]);
    const int b_ = row0 >> 12;
    const int n0_ = row0 & 4095;
#pragma unroll
    for (int p = 0; p < 4; ++p) {
      __syncthreads();
      if (wm == (p >> 1)) {
        const int mi0 = (p & 1) * 4;
#pragma unroll
        for (int mi4 = 0; mi4 < 4; ++mi4) {
#pragma unroll
          for (int ni = 0; ni < 4; ++ni) {
            int c = wn * 64 + ni * 16 + l15;
            ushort4v tv;
#pragma unroll
            for (int r = 0; r < 4; ++r) tv[r] = f2bf(acc[mi0 + mi4][ni][r]);
            *(ushort4v*)&T[c][mi4 * 16 + l4 * 4] = tv;
          }
        }
      }
      __syncthreads();
#pragma unroll
      for (int i = 0; i < 4; ++i) {
        int u = i * 512 + tid;
        int c = u >> 3, nc = (u & 7) * 8;
        int h = (col0g + c) >> 6, d = c & 63;
        short8 v = *(const short8*)&T[c][nc];
        *(short8*)(vT + ((size_t)((b_ * 16 + h) * 64 + d)) * 4096 + n0_ + p * 64 + nc) = v;
      }
    }
  }
}

// ---------------- fused phi(k) + kv: gload16 staging, prefetch, swizzled LDS ----------------
// kt/vt: [64][64] linear, 128B rows = 8 16B-slots; phys slot = logical ^ (row&7).
__global__ __launch_bounds__(256) void k_kv(const ushort_t* __restrict__ qkv,
                                            const ushort_t* __restrict__ vT,
                                            const _Float16* __restrict__ om,
                                            float* __restrict__ kv,
                                            float* __restrict__ pksum) {
  __shared__ _Float16 kt2[2][4096];  // 8 KB each
  __shared__ ushort_t vt2[2][4096];
  __shared__ ushort_t pk[256][72];   // [m][n], rows 144B
  __shared__ float nrm[64];
  const int bh = blockIdx.x, split = blockIdx.y;
  const int b = bh >> 4, h = bh & 15;
  const int tid = threadIdx.x, lane = tid & 63, w = tid >> 6;
  const int l15 = lane & 15, l4 = lane >> 4;

  int srow[2], scol[2], sdst[2];
#pragma unroll
  for (int i = 0; i < 2; ++i) {
    int u = i * 256 + tid;
    srow[i] = u >> 3;
    scol[i] = ((u & 7) ^ (srow[i] & 7)) * 8;  // pre-swizzled source col (elems)
    sdst[i] = u * 8;                          // linear LDS dst (elems)
  }
  auto stage = [&](int buf, int c) {
    const int nbase = split * 512 + c * 64;
#pragma unroll
    for (int i = 0; i < 2; ++i) {
      gload16(qkv + (size_t)(b * 4096 + nbase + srow[i]) * QKV_LD + 1024 + h * 64 + scol[i],
              &kt2[buf][sdst[i]]);
      gload16(vT + (size_t)(bh * 64 + srow[i]) * 4096 + nbase + scol[i], &vt2[buf][sdst[i]]);
    }
  };

  half8 bom[4][2];
#pragma unroll
  for (int mf = 0; mf < 4; ++mf)
#pragma unroll
    for (int ks = 0; ks < 2; ++ks)
      bom[mf][ks] = *(const half8*)(om + (size_t)(w * 64 + mf * 16 + l15) * 64 + ks * 32 + l4 * 8);

  f32x4 kvacc[4][4] = {};
  float psum[4] = {0.f, 0.f, 0.f, 0.f};

  stage(0, 0);
#pragma unroll 1
  for (int c = 0; c < 8; ++c) {
    const int cb = c & 1;
    ENTRY_BAR;  // drains stage(c); pk/nrm WAR vs prev chunk
    if (c < 7) stage(cb ^ 1, c + 1);
    {  // norms: 4 threads/row, vectorized b128 reads
      int row = tid >> 2, p = tid & 3;
      const _Float16* base = &kt2[cb][row * 64];
      half8 x0 = *(const half8*)&base[((2 * p) ^ (row & 7)) * 8];
      half8 x1 = *(const half8*)&base[((2 * p + 1) ^ (row & 7)) * 8];
      float sm = 0.f;
#pragma unroll
      for (int e = 0; e < 8; ++e) {
        float a = (float)x0[e], bb2 = (float)x1[e];
        sm += a * a + bb2 * bb2;
      }
      sm += __shfl_xor(sm, 1);
      sm += __shfl_xor(sm, 2);
      if ((tid & 3) == 0) nrm[row] = 0.5f * sm;
    }
    MID_BAR;
#pragma unroll
    for (int nf = 0; nf < 4; ++nf) {
      int arow = nf * 16 + l15;
      const _Float16* base = &kt2[cb][arow * 64];
      half8 a0 = *(const half8*)&base[(l4 ^ (arow & 7)) * 8];
      half8 a1 = *(const half8*)&base[((4 + l4) ^ (arow & 7)) * 8];
#pragma unroll
      for (int mf = 0; mf < 4; ++mf) {
        f32x4 f = {};
        f = __builtin_amdgcn_mfma_f32_16x16x32_f16(a0, bom[mf][0], f, 0, 0, 0);
        f = __builtin_amdgcn_mfma_f32_16x16x32_f16(a1, bom[mf][1], f, 0, 0, 0);
        ushort4v pw;
#pragma unroll
        for (int r = 0; r < 4; ++r) {
          int n = nf * 16 + l4 * 4 + r;
          float p = __expf(f[r] - nrm[n]) * 0.0625f;
          psum[mf] += p;
          pw[r] = f2bf(p);
        }
        *(ushort4v*)&pk[w * 64 + mf * 16 + l15][nf * 16 + l4 * 4] = pw;
      }
    }
    MID_BAR;
#pragma unroll
    for (int ks = 0; ks < 2; ++ks) {
      short8 pa[4];
#pragma unroll
      for (int mf = 0; mf < 4; ++mf)
        pa[mf] = *(const short8*)&pk[w * 64 + mf * 16 + l15][ks * 32 + l4 * 8];
#pragma unroll
      for (int df = 0; df < 4; ++df) {
        int vrow = df * 16 + l15;
        short8 bv = *(const short8*)&vt2[cb][vrow * 64 + ((4 * ks + l4) ^ (vrow & 7)) * 8];
#pragma unroll
        for (int mf = 0; mf < 4; ++mf)
          kvacc[mf][df] = __builtin_amdgcn_mfma_f32_16x16x32_bf16(pa[mf], bv, kvacc[mf][df], 0, 0, 0);
      }
    }
  }
#pragma unroll
  for (int mf = 0; mf < 4; ++mf)
#pragma unroll
    for (int df = 0; df < 4; ++df)
#pragma unroll
      for (int r = 0; r < 4; ++r) {
        int m = w * 64 + mf * 16 + l4 * 4 + r;
        int d = df * 16 + l15;
        atomicAdd(&kv[((size_t)bh * 256 + m) * 64 + d], kvacc[mf][df][r]);
      }
#pragma unroll
  for (int mf = 0; mf < 4; ++mf) {
    float v = psum[mf];
    v += __shfl_xor(v, 16);
    v += __shfl_xor(v, 32);
    if (lane < 16) atomicAdd(&pksum[bh * 256 + w * 64 + mf * 16 + lane], v);
  }
}

// ---------------- fused phi(q) + out (kv transpose folded in, prefetched q) ----------------
// LDS: kvl 42.2K + qt2 32K + pq 67.6K + nrm 0.5K = 142.3K (1 block/CU).
__global__ __launch_bounds__(512) void k_out(const ushort_t* __restrict__ qkv,
                                             const float* __restrict__ kv,
                                             const float* __restrict__ pksum,
                                             const _Float16* __restrict__ om,
                                             float* __restrict__ outp) {
  __shared__ ushort_t kvl[80][264];
  __shared__ _Float16 qt2[2][8192];  // [128][64] f16 swizzled, 16 KB each
  __shared__ ushort_t pq[128][264];  // pq^T [n][m]; its memory first used as pqf f32
  __shared__ float nrm[128];
  const int bh = blockIdx.x, ns = blockIdx.y;
  const int b = bh >> 4, h = bh & 15;
  const int tid = threadIdx.x, lane = tid & 63, w = tid >> 6;
  const int l15 = lane & 15, l4 = lane >> 4;
  const int wn = w >> 2, wm = w & 3;

  // ---- build kvl: stage kv f32 coalesced into swizzled pqf, transpose to bf16 ----
  float* pqf = (float*)&pq[0][0];  // [256 rows][16 f32x4-slots], slot ^= row&15
#pragma unroll
  for (int i = 0; i < 8; ++i) {
    int u = i * 512 + tid;  // 4096 float4 units
    int r = u >> 4, s = u & 15;
    float4 v = *(const float4*)(kv + ((size_t)bh * 256 + r) * 64 + s * 4);
    *(float4*)&pqf[r * 64 + (s ^ (r & 15)) * 4] = v;
  }
  __syncthreads();
  {
    int j = tid >> 3, mb = (tid & 7) * 32;  // j = d-row of kvl
#pragma unroll
    for (int gb = 0; gb < 4; ++gb) {
      short8 pack;
#pragma unroll
      for (int e = 0; e < 8; ++e) {
        int m = mb + gb * 8 + e;
        float v = pqf[m * 64 + (((j >> 2) ^ (m & 15)) * 4) + (j & 3)];
        pack[e] = (short)f2bf(v);
      }
      *(short8*)&kvl[j][mb + gb * 8] = pack;
    }
  }
  if (tid < 256) {
    kvl[64][tid] = f2bf(pksum[bh * 256 + tid]);
#pragma unroll
    for (int r = 65; r < 80; ++r) kvl[r][tid] = 0;
  }

  // ---- q staging (gload16, swizzled) ----
  int srow[2], scol[2], sdst[2];
#pragma unroll
  for (int i = 0; i < 2; ++i) {
    int u = i * 512 + tid;
    srow[i] = u >> 3;
    scol[i] = ((u & 7) ^ (srow[i] & 7)) * 8;
    sdst[i] = u * 8;
  }
  auto stageQ = [&](int buf, int ch) {
    const int n0 = ns * 512 + ch * 128;
#pragma unroll
    for (int i = 0; i < 2; ++i)
      gload16((const _Float16*)qkv + (size_t)(b * 4096 + n0 + srow[i]) * QKV_LD + h * 64 + scol[i],
              &qt2[buf][sdst[i]]);
  };

  half8 bom[4][2];
#pragma unroll
  for (int mf = 0; mf < 4; ++mf)
#pragma unroll
    for (int ks = 0; ks < 2; ++ks)
      bom[mf][ks] = *(const half8*)(om + (size_t)(wm * 64 + mf * 16 + l15) * 64 + ks * 32 + l4 * 8);

  stageQ(0, 0);
#pragma unroll 1
  for (int ch = 0; ch < 4; ++ch) {
    const int cb = ch & 1;
    const int n0 = ns * 512 + ch * 128;
    ENTRY_BAR;  // drains stageQ(ch); kvl-build + pq WAR visibility
    if (ch < 3) stageQ(cb ^ 1, ch + 1);
    {  // norms: 4 threads/row over 128 rows
      int row = tid >> 2, p = tid & 3;
      const _Float16* base = &qt2[cb][row * 64];
      half8 x0 = *(const half8*)&base[((2 * p) ^ (row & 7)) * 8];
      half8 x1 = *(const half8*)&base[((2 * p + 1) ^ (row & 7)) * 8];
      float sm = 0.f;
#pragma unroll
      for (int e = 0; e < 8; ++e) {
        float a = (float)x0[e], bb2 = (float)x1[e];
        sm += a * a + bb2 * bb2;
      }
      sm += __shfl_xor(sm, 1);
      sm += __shfl_xor(sm, 2);
      if ((tid & 3) == 0) nrm[row] = 0.5f * sm;
    }
    MID_BAR;
#pragma unroll
    for (int nf = 0; nf < 4; ++nf) {
      int arow = wn * 64 + nf * 16 + l15;
      const _Float16* base = &qt2[cb][arow * 64];
      half8 qa0 = *(const half8*)&base[(l4 ^ (arow & 7)) * 8];
      half8 qa1 = *(const half8*)&base[((4 + l4) ^ (arow & 7)) * 8];
      float nr = nrm[arow];
#pragma unroll
      for (int mf = 0; mf < 4; ++mf) {
        f32x4 f = {};
        f = __builtin_amdgcn_mfma_f32_16x16x32_f16(bom[mf][0], qa0, f, 0, 0, 0);
        f = __builtin_amdgcn_mfma_f32_16x16x32_f16(bom[mf][1], qa1, f, 0, 0, 0);
        ushort4v pw;
#pragma unroll
        for (int r = 0; r < 4; ++r) {
          float p = __expf(f[r] - nr) * 0.0625f;
          pw[r] = f2bf(p);
        }
        *(ushort4v*)&pq[wn * 64 + nf * 16 + l15][wm * 64 + mf * 16 + l4 * 4] = pw;
      }
    }
    MID_BAR;
    f32x4 oacc[5] = {};
#pragma unroll
    for (int ks = 0; ks < 8; ++ks) {
      short8 pa = *(const short8*)&pq[w * 16 + l15][ks * 32 + l4 * 8];
#pragma unroll
      for (int cf = 0; cf < 5; ++cf) {
        short8 bv = *(const short8*)&kvl[cf * 16 + l15][ks * 32 + l4 * 8];
        oacc[cf] = __builtin_amdgcn_mfma_f32_16x16x32_bf16(pa, bv, oacc[cf], 0, 0, 0);
      }
    }
#pragma unroll
    for (int r = 0; r < 4; ++r) {
      float z = __shfl(oacc[4][r], lane & 48);
      float inv = 1.0f / (z + 1e-6f);
      int n = n0 + w * 16 + l4 * 4 + r;
#pragma unroll
      for (int cf = 0; cf < 4; ++cf)
        outp[(size_t)(b * 4096 + n) * 1024 + h * 64 + cf * 16 + l15] = oacc[cf][r] * inv;
    }
  }
}

extern "C" void kernel_launch(void* const* d_in, const int* in_sizes, int n_in,
                              void* d_out, int out_size, void* d_ws, size_t ws_size,
                              hipStream_t stream) {
  const float* x = (const float*)d_in[0];
  const float* Wq = (const float*)d_in[1];
  const float* Wk = (const float*)d_in[2];
  const float* Wv = (const float*)d_in[3];
  const float* omg = (const float*)d_in[4];
  float* outp = (float*)d_out;
  char* ws = (char*)d_ws;

  _Float16* wt = (_Float16*)(ws);                 // 6,291,456
  _Float16* om = (_Float16*)(ws + 6291456);       //    32,768
  ushort_t* qkv = (ushort_t*)(ws + 6324224);      // 67,108,864 (Q|K, stride 2048)
  ushort_t* vT = (ushort_t*)(ws + 73433088);      // 33,554,432
  _Float16* xh = (_Float16*)(ws + 106987520);     // 33,554,432
  float* kv = (float*)(ws + 140541952);           // 4,194,304
  float* pksum = (float*)(ws + 144736256);        //    65,536

  k_wtrans<<<dim3(32, 32, 4), dim3(32, 8), 0, stream>>>(Wq, Wk, Wv, omg, wt, om);
  k_xconv<<<dim3(8192), dim3(256), 0, stream>>>(x, xh);
  k_gemm<<<dim3(768), dim3(512), 0, stream>>>(xh, wt, qkv, vT);
  hipMemsetAsync(kv, 0, 4194304 + 65536, stream);  // kv + pksum (contiguous)
  k_kv<<<dim3(64, 8), dim3(256), 0, stream>>>(qkv, vT, om, kv, pksum);
  k_out<<<dim3(64, 8), dim3(512), 0, stream>>>(qkv, kv, pksum, om, outp);
}

// Round 12
// 233.273 us; speedup vs baseline: 1.1400x; 1.0452x over previous
//
#include <hip/hip_runtime.h>

// Performer (FAVOR+) attention, MI355X.
// B=4 N=4096 H=16 D=64 DIM=1024 M=256.
// Pipeline (6 launches):
//  k_wtrans:  W f32 -> wt[g][n][k] fp16 (B^T); z==3 slice converts omega->fp16
//  k_xconv:   x f32 -> xh fp16
//  k_gemm:    r6 structure (111us/40%): 256x256, BK=32, ring-4 LDS,
//             counted vmcnt(6), 1 barrier/K-tile, setprio, XOR swizzle;
//             Q,K -> qkv fp16 (stride 2048); V -> vT bf16 in-epilogue.
//  k_kv:      gload16-staged kt/vt, 1-chunk prefetch; per-SPLIT private
//             output slices kvp[8]/pksump[8] (plain stores, NO atomics;
//             kvp aliases dead xh). r12: atomics removed.
//  k_red:     kv = sum_s kvp[s]; pksum = sum_s pksump[s]  (38 MB stream)
//  k_out:     kv f32 transposed in-LDS, kvl+pq resident, gload16 q staged
//             (issued BEFORE kvl build); out = (pq@kv)/(pq@pksum+1e-6)

typedef _Float16 half8 __attribute__((ext_vector_type(8)));
typedef short short8 __attribute__((ext_vector_type(8)));
typedef float f32x4 __attribute__((ext_vector_type(4)));
typedef unsigned short ushort4v __attribute__((ext_vector_type(4)));
typedef unsigned short ushort_t;
typedef unsigned int uint_t;

#define QKV_LD 2048

__device__ __forceinline__ ushort_t f2bf(float f) {
  uint_t u = __builtin_bit_cast(uint_t, f);
  u += 0x7fffu + ((u >> 16) & 1u);
  return (ushort_t)(u >> 16);
}

__device__ __forceinline__ void gload16(const void* g, void* l) {
  __builtin_amdgcn_global_load_lds(
      (const __attribute__((address_space(1))) void*)g,
      (__attribute__((address_space(3))) void*)l, 16, 0, 0);
}

#define ENTRY_BAR                                                  \
  asm volatile("s_waitcnt vmcnt(0) lgkmcnt(0)" ::: "memory");      \
  asm volatile("s_barrier" ::: "memory")
#define MID_BAR                                                    \
  asm volatile("s_waitcnt lgkmcnt(0)" ::: "memory");               \
  asm volatile("s_barrier" ::: "memory")

// ---------------- W transpose+convert (+ omega convert on z==3) ----------------
__global__ void k_wtrans(const float* __restrict__ Wq, const float* __restrict__ Wk,
                         const float* __restrict__ Wv, const float* __restrict__ omega,
                         _Float16* __restrict__ wt, _Float16* __restrict__ om) {
  const int g = blockIdx.z;
  const int tx = threadIdx.x, ty = threadIdx.y;
  if (g == 3) {
    int idx = blockIdx.y * 32 + blockIdx.x;
    if (idx < 64) {
      int i = idx * 256 + ty * 32 + tx;
      om[i] = (_Float16)omega[i];
    }
    return;
  }
  __shared__ float t[32][33];
  const float* W = (g == 0) ? Wq : ((g == 1) ? Wk : Wv);
  const int n0 = blockIdx.x * 32, k0 = blockIdx.y * 32;
#pragma unroll
  for (int j = 0; j < 4; ++j)
    t[ty + j * 8][tx] = W[(size_t)(k0 + ty + j * 8) * 1024 + n0 + tx];
  __syncthreads();
  _Float16* o = wt + (size_t)g * 1024 * 1024;
#pragma unroll
  for (int j = 0; j < 4; ++j)
    o[(size_t)(n0 + ty + j * 8) * 1024 + k0 + tx] = (_Float16)t[tx][ty + j * 8];
}

// ---------------- x convert: xh[n][k] = (f16)x[n][k] ----------------
__global__ __launch_bounds__(256) void k_xconv(const float* __restrict__ x,
                                               _Float16* __restrict__ xh) {
  size_t base = ((size_t)blockIdx.x * 256 + threadIdx.x) * 8;
  float4 f0 = *(const float4*)(x + base);
  float4 f1 = *(const float4*)(x + base + 4);
  half8 h;
  h[0] = (_Float16)f0.x; h[1] = (_Float16)f0.y; h[2] = (_Float16)f0.z; h[3] = (_Float16)f0.w;
  h[4] = (_Float16)f1.x; h[5] = (_Float16)f1.y; h[6] = (_Float16)f1.z; h[7] = (_Float16)f1.w;
  *(half8*)(xh + base) = h;
}

// ---------------- QKV GEMM: r6 structure (256x256, BK=32, ring-4, 1 bar/K-tile) ----------------
__global__ __launch_bounds__(512, 2) void k_gemm(const _Float16* __restrict__ xh,
                                                 const _Float16* __restrict__ wt,
                                                 ushort_t* __restrict__ qkv,
                                                 ushort_t* __restrict__ vT) {
  __shared__ _Float16 As[4][8192];  // 64 KB; T (36 KB) aliases As in epilogue
  __shared__ _Float16 Bs[4][8192];  // 64 KB
  const int vb = (blockIdx.x & 7) * 96 + (blockIdx.x >> 3);
  const int ct = vb % 12, rt = vb / 12;
  const int col0 = ct * 256, row0 = rt * 256;
  const int g = col0 >> 10;  // 0=Q 1=K 2=V
  const int col0g = col0 & 1023;
  const _Float16* wtg = wt + (size_t)g * (1024 * 1024);
  const int tid = threadIdx.x;
  const int lane = tid & 63;
  const int w = tid >> 6;
  const int wm = w >> 2, wn = w & 3;
  const int l15 = lane & 15, l4 = lane >> 4;

  int srow[2], scol[2], dst[2];
#pragma unroll
  for (int i = 0; i < 2; ++i) {
    int u = i * 512 + tid;
    int rb = u >> 6, rr = (u >> 2) & 15, ccb = u & 3;
    srow[i] = rb * 16 + rr;
    scol[i] = (ccb * 8) ^ ((rr & 8) ? 16 : 0);
    dst[i] = u * 8;
  }
  const int kx = (l4 * 8) ^ ((l15 & 8) ? 16 : 0);

  auto stageA = [&](int b, int kt) {
#pragma unroll
    for (int i = 0; i < 2; ++i)
      gload16(xh + (size_t)(row0 + srow[i]) * 1024 + kt * 32 + scol[i], &As[b][dst[i]]);
  };
  auto stageB = [&](int b, int kt) {
#pragma unroll
    for (int i = 0; i < 2; ++i)
      gload16(wtg + (size_t)(col0g + srow[i]) * 1024 + kt * 32 + scol[i], &Bs[b][dst[i]]);
  };

  f32x4 acc[8][4] = {};

  stageA(0, 0); stageB(0, 0);
  stageA(1, 1); stageB(1, 1);

  for (int kt = 0; kt < 32; ++kt) {
    const int b = kt & 3, b2 = (kt + 2) & 3;
    if (kt < 30) stageA(b2, kt + 2);
    if (kt < 30)       asm volatile("s_waitcnt vmcnt(6)" ::: "memory");
    else if (kt == 30) asm volatile("s_waitcnt vmcnt(4)" ::: "memory");
    else               asm volatile("s_waitcnt vmcnt(0)" ::: "memory");
    asm volatile("s_barrier" ::: "memory");

    const _Float16* Ab = &As[b][0];
    const _Float16* Bb = &Bs[b][0];
    half8 av[4], bv[4];
#pragma unroll
    for (int mi = 0; mi < 4; ++mi)
      av[mi] = *(const half8*)&Ab[(wm * 8 + mi) * 512 + l15 * 32 + kx];
#pragma unroll
    for (int ni = 0; ni < 4; ++ni)
      bv[ni] = *(const half8*)&Bb[(wn * 4 + ni) * 512 + l15 * 32 + kx];
    if (kt < 30) stageB(b2, kt + 2);
    __builtin_amdgcn_s_setprio(1);
#pragma unroll
    for (int mi = 0; mi < 4; ++mi)
#pragma unroll
      for (int ni = 0; ni < 4; ++ni)
        acc[mi][ni] = __builtin_amdgcn_mfma_f32_16x16x32_f16(av[mi], bv[ni], acc[mi][ni], 0, 0, 0);
    __builtin_amdgcn_s_setprio(0);

    half8 av2[4];
#pragma unroll
    for (int mi = 0; mi < 4; ++mi)
      av2[mi] = *(const half8*)&Ab[(wm * 8 + 4 + mi) * 512 + l15 * 32 + kx];
    __builtin_amdgcn_s_setprio(1);
#pragma unroll
    for (int mi = 0; mi < 4; ++mi)
#pragma unroll
      for (int ni = 0; ni < 4; ++ni)
        acc[4 + mi][ni] = __builtin_amdgcn_mfma_f32_16x16x32_f16(av2[mi], bv[ni], acc[4 + mi][ni], 0, 0, 0);
    __builtin_amdgcn_s_setprio(0);
  }

  if (g < 2) {
#pragma unroll
    for (int mi = 0; mi < 8; ++mi) {
      int gr0 = row0 + wm * 128 + mi * 16 + l4 * 4;
#pragma unroll
      for (int ni = 0; ni < 4; ++ni) {
        int gc = col0 + wn * 64 + ni * 16 + l15;
#pragma unroll
        for (int r = 0; r < 4; ++r)
          qkv[(size_t)(gr0 + r) * QKV_LD + gc] =
              __builtin_bit_cast(ushort_t, (_Float16)acc[mi][ni][r]);
      }
    }
  } else {
    ushort_t(*T)[72] = reinterpret_cast<ushort_t(*)[72]>(&As[0][0]);
    const int b_ = row0 >> 12;
    const int n0_ = row0 & 4095;
#pragma unroll
    for (int p = 0; p < 4; ++p) {
      __syncthreads();
      if (wm == (p >> 1)) {
        const int mi0 = (p & 1) * 4;
#pragma unroll
        for (int mi4 = 0; mi4 < 4; ++mi4) {
#pragma unroll
          for (int ni = 0; ni < 4; ++ni) {
            int c = wn * 64 + ni * 16 + l15;
            ushort4v tv;
#pragma unroll
            for (int r = 0; r < 4; ++r) tv[r] = f2bf(acc[mi0 + mi4][ni][r]);
            *(ushort4v*)&T[c][mi4 * 16 + l4 * 4] = tv;
          }
        }
      }
      __syncthreads();
#pragma unroll
      for (int i = 0; i < 4; ++i) {
        int u = i * 512 + tid;
        int c = u >> 3, nc = (u & 7) * 8;
        int h = (col0g + c) >> 6, d = c & 63;
        short8 v = *(const short8*)&T[c][nc];
        *(short8*)(vT + ((size_t)((b_ * 16 + h) * 64 + d)) * 4096 + n0_ + p * 64 + nc) = v;
      }
    }
  }
}

// ---------------- fused phi(k) + kv: per-split private outputs (no atomics) ----------------
__global__ __launch_bounds__(256) void k_kv(const ushort_t* __restrict__ qkv,
                                            const ushort_t* __restrict__ vT,
                                            const _Float16* __restrict__ om,
                                            float* __restrict__ kvp,
                                            float* __restrict__ pksump) {
  __shared__ _Float16 kt2[2][4096];  // 8 KB each
  __shared__ ushort_t vt2[2][4096];
  __shared__ ushort_t pk[256][72];   // [m][n], rows 144B
  __shared__ float nrm[64];
  const int bh = blockIdx.x, split = blockIdx.y;
  const int b = bh >> 4, h = bh & 15;
  const int tid = threadIdx.x, lane = tid & 63, w = tid >> 6;
  const int l15 = lane & 15, l4 = lane >> 4;

  int srow[2], scol[2], sdst[2];
#pragma unroll
  for (int i = 0; i < 2; ++i) {
    int u = i * 256 + tid;
    srow[i] = u >> 3;
    scol[i] = ((u & 7) ^ (srow[i] & 7)) * 8;
    sdst[i] = u * 8;
  }
  auto stage = [&](int buf, int c) {
    const int nbase = split * 512 + c * 64;
#pragma unroll
    for (int i = 0; i < 2; ++i) {
      gload16(qkv + (size_t)(b * 4096 + nbase + srow[i]) * QKV_LD + 1024 + h * 64 + scol[i],
              &kt2[buf][sdst[i]]);
      gload16(vT + (size_t)(bh * 64 + srow[i]) * 4096 + nbase + scol[i], &vt2[buf][sdst[i]]);
    }
  };

  half8 bom[4][2];
#pragma unroll
  for (int mf = 0; mf < 4; ++mf)
#pragma unroll
    for (int ks = 0; ks < 2; ++ks)
      bom[mf][ks] = *(const half8*)(om + (size_t)(w * 64 + mf * 16 + l15) * 64 + ks * 32 + l4 * 8);

  f32x4 kvacc[4][4] = {};
  float psum[4] = {0.f, 0.f, 0.f, 0.f};

  stage(0, 0);
#pragma unroll 1
  for (int c = 0; c < 8; ++c) {
    const int cb = c & 1;
    ENTRY_BAR;
    if (c < 7) stage(cb ^ 1, c + 1);
    {
      int row = tid >> 2, p = tid & 3;
      const _Float16* base = &kt2[cb][row * 64];
      half8 x0 = *(const half8*)&base[((2 * p) ^ (row & 7)) * 8];
      half8 x1 = *(const half8*)&base[((2 * p + 1) ^ (row & 7)) * 8];
      float sm = 0.f;
#pragma unroll
      for (int e = 0; e < 8; ++e) {
        float a = (float)x0[e], bb2 = (float)x1[e];
        sm += a * a + bb2 * bb2;
      }
      sm += __shfl_xor(sm, 1);
      sm += __shfl_xor(sm, 2);
      if ((tid & 3) == 0) nrm[row] = 0.5f * sm;
    }
    MID_BAR;
#pragma unroll
    for (int nf = 0; nf < 4; ++nf) {
      int arow = nf * 16 + l15;
      const _Float16* base = &kt2[cb][arow * 64];
      half8 a0 = *(const half8*)&base[(l4 ^ (arow & 7)) * 8];
      half8 a1 = *(const half8*)&base[((4 + l4) ^ (arow & 7)) * 8];
#pragma unroll
      for (int mf = 0; mf < 4; ++mf) {
        f32x4 f = {};
        f = __builtin_amdgcn_mfma_f32_16x16x32_f16(a0, bom[mf][0], f, 0, 0, 0);
        f = __builtin_amdgcn_mfma_f32_16x16x32_f16(a1, bom[mf][1], f, 0, 0, 0);
        ushort4v pw;
#pragma unroll
        for (int r = 0; r < 4; ++r) {
          int n = nf * 16 + l4 * 4 + r;
          float p = __expf(f[r] - nrm[n]) * 0.0625f;
          psum[mf] += p;
          pw[r] = f2bf(p);
        }
        *(ushort4v*)&pk[w * 64 + mf * 16 + l15][nf * 16 + l4 * 4] = pw;
      }
    }
    MID_BAR;
#pragma unroll
    for (int ks = 0; ks < 2; ++ks) {
      short8 pa[4];
#pragma unroll
      for (int mf = 0; mf < 4; ++mf)
        pa[mf] = *(const short8*)&pk[w * 64 + mf * 16 + l15][ks * 32 + l4 * 8];
#pragma unroll
      for (int df = 0; df < 4; ++df) {
        int vrow = df * 16 + l15;
        short8 bv = *(const short8*)&vt2[cb][vrow * 64 + ((4 * ks + l4) ^ (vrow & 7)) * 8];
#pragma unroll
        for (int mf = 0; mf < 4; ++mf)
          kvacc[mf][df] = __builtin_amdgcn_mfma_f32_16x16x32_bf16(pa[mf], bv, kvacc[mf][df], 0, 0, 0);
      }
    }
  }
  // per-split private slice: plain stores, each (m,d) written exactly once
  float* slice = kvp + (size_t)(split * 64 + bh) * 16384;
#pragma unroll
  for (int mf = 0; mf < 4; ++mf)
#pragma unroll
    for (int df = 0; df < 4; ++df)
#pragma unroll
      for (int r = 0; r < 4; ++r) {
        int m = w * 64 + mf * 16 + l4 * 4 + r;
        int d = df * 16 + l15;
        slice[m * 64 + d] = kvacc[mf][df][r];
      }
#pragma unroll
  for (int mf = 0; mf < 4; ++mf) {
    float v = psum[mf];
    v += __shfl_xor(v, 16);
    v += __shfl_xor(v, 32);
    if (lane < 16)
      pksump[(size_t)(split * 64 + bh) * 256 + w * 64 + mf * 16 + lane] = v;
  }
}

// ---------------- reduce per-split slices: kv = sum kvp, pksum = sum pksump ----------------
__global__ __launch_bounds__(256) void k_red(const float* __restrict__ kvp,
                                             const float* __restrict__ pksump,
                                             float* __restrict__ kv,
                                             float* __restrict__ pksum) {
  const int bid = blockIdx.x, tid = threadIdx.x;
  if (bid < 1024) {
    size_t j = ((size_t)bid * 256 + tid) * 4;  // float4 index into 4 MB kv
    f32x4 s = {};
#pragma unroll
    for (int sp = 0; sp < 8; ++sp) {
      f32x4 v = *(const f32x4*)(kvp + (size_t)sp * 1048576 + j);
      s += v;
    }
    *(f32x4*)(kv + j) = s;
  } else {
    size_t j = ((size_t)(bid - 1024) * 256 + tid) * 4;  // float4 into 64 KB pksum
    f32x4 s = {};
#pragma unroll
    for (int sp = 0; sp < 8; ++sp) {
      f32x4 v = *(const f32x4*)(pksump + (size_t)sp * 16384 + j);
      s += v;
    }
    *(f32x4*)(pksum + j) = s;
  }
}

// ---------------- fused phi(q) + out (kv transpose folded in, prefetched q) ----------------
__global__ __launch_bounds__(512) void k_out(const ushort_t* __restrict__ qkv,
                                             const float* __restrict__ kv,
                                             const float* __restrict__ pksum,
                                             const _Float16* __restrict__ om,
                                             float* __restrict__ outp) {
  __shared__ ushort_t kvl[80][264];
  __shared__ _Float16 qt2[2][8192];
  __shared__ ushort_t pq[128][264];  // pq^T [n][m]; first used as pqf f32
  __shared__ float nrm[128];
  const int bh = blockIdx.x, ns = blockIdx.y;
  const int b = bh >> 4, h = bh & 15;
  const int tid = threadIdx.x, lane = tid & 63, w = tid >> 6;
  const int l15 = lane & 15, l4 = lane >> 4;
  const int wn = w >> 2, wm = w & 3;

  // q staging coords + issue chunk0 FIRST (DMA overlaps kvl build)
  int srow[2], scol[2], sdst[2];
#pragma unroll
  for (int i = 0; i < 2; ++i) {
    int u = i * 512 + tid;
    srow[i] = u >> 3;
    scol[i] = ((u & 7) ^ (srow[i] & 7)) * 8;
    sdst[i] = u * 8;
  }
  auto stageQ = [&](int buf, int ch) {
    const int n0 = ns * 512 + ch * 128;
#pragma unroll
    for (int i = 0; i < 2; ++i)
      gload16((const _Float16*)qkv + (size_t)(b * 4096 + n0 + srow[i]) * QKV_LD + h * 64 + scol[i],
              &qt2[buf][sdst[i]]);
  };
  stageQ(0, 0);

  // ---- build kvl: stage kv f32 coalesced into swizzled pqf, transpose to bf16 ----
  float* pqf = (float*)&pq[0][0];  // [256 rows][16 f32x4-slots], slot ^= row&15
#pragma unroll
  for (int i = 0; i < 8; ++i) {
    int u = i * 512 + tid;
    int r = u >> 4, s = u & 15;
    float4 v = *(const float4*)(kv + ((size_t)bh * 256 + r) * 64 + s * 4);
    *(float4*)&pqf[r * 64 + (s ^ (r & 15)) * 4] = v;
  }
  __syncthreads();
  {
    int j = tid >> 3, mb = (tid & 7) * 32;
#pragma unroll
    for (int gb = 0; gb < 4; ++gb) {
      short8 pack;
#pragma unroll
      for (int e = 0; e < 8; ++e) {
        int m = mb + gb * 8 + e;
        float v = pqf[m * 64 + (((j >> 2) ^ (m & 15)) * 4) + (j & 3)];
        pack[e] = (short)f2bf(v);
      }
      *(short8*)&kvl[j][mb + gb * 8] = pack;
    }
  }
  if (tid < 256) {
    kvl[64][tid] = f2bf(pksum[bh * 256 + tid]);
#pragma unroll
    for (int r = 65; r < 80; ++r) kvl[r][tid] = 0;
  }

  half8 bom[4][2];
#pragma unroll
  for (int mf = 0; mf < 4; ++mf)
#pragma unroll
    for (int ks = 0; ks < 2; ++ks)
      bom[mf][ks] = *(const half8*)(om + (size_t)(wm * 64 + mf * 16 + l15) * 64 + ks * 32 + l4 * 8);

#pragma unroll 1
  for (int ch = 0; ch < 4; ++ch) {
    const int cb = ch & 1;
    const int n0 = ns * 512 + ch * 128;
    ENTRY_BAR;
    if (ch < 3) stageQ(cb ^ 1, ch + 1);
    {
      int row = tid >> 2, p = tid & 3;
      const _Float16* base = &qt2[cb][row * 64];
      half8 x0 = *(const half8*)&base[((2 * p) ^ (row & 7)) * 8];
      half8 x1 = *(const half8*)&base[((2 * p + 1) ^ (row & 7)) * 8];
      float sm = 0.f;
#pragma unroll
      for (int e = 0; e < 8; ++e) {
        float a = (float)x0[e], bb2 = (float)x1[e];
        sm += a * a + bb2 * bb2;
      }
      sm += __shfl_xor(sm, 1);
      sm += __shfl_xor(sm, 2);
      if ((tid & 3) == 0) nrm[row] = 0.5f * sm;
    }
    MID_BAR;
#pragma unroll
    for (int nf = 0; nf < 4; ++nf) {
      int arow = wn * 64 + nf * 16 + l15;
      const _Float16* base = &qt2[cb][arow * 64];
      half8 qa0 = *(const half8*)&base[(l4 ^ (arow & 7)) * 8];
      half8 qa1 = *(const half8*)&base[((4 + l4) ^ (arow & 7)) * 8];
      float nr = nrm[arow];
#pragma unroll
      for (int mf = 0; mf < 4; ++mf) {
        f32x4 f = {};
        f = __builtin_amdgcn_mfma_f32_16x16x32_f16(bom[mf][0], qa0, f, 0, 0, 0);
        f = __builtin_amdgcn_mfma_f32_16x16x32_f16(bom[mf][1], qa1, f, 0, 0, 0);
        ushort4v pw;
#pragma unroll
        for (int r = 0; r < 4; ++r) {
          float p = __expf(f[r] - nr) * 0.0625f;
          pw[r] = f2bf(p);
        }
        *(ushort4v*)&pq[wn * 64 + nf * 16 + l15][wm * 64 + mf * 16 + l4 * 4] = pw;
      }
    }
    MID_BAR;
    f32x4 oacc[5] = {};
#pragma unroll
    for (int ks = 0; ks < 8; ++ks) {
      short8 pa = *(const short8*)&pq[w * 16 + l15][ks * 32 + l4 * 8];
#pragma unroll
      for (int cf = 0; cf < 5; ++cf) {
        short8 bv = *(const short8*)&kvl[cf * 16 + l15][ks * 32 + l4 * 8];
        oacc[cf] = __builtin_amdgcn_mfma_f32_16x16x32_bf16(pa, bv, oacc[cf], 0, 0, 0);
      }
    }
#pragma unroll
    for (int r = 0; r < 4; ++r) {
      float z = __shfl(oacc[4][r], lane & 48);
      float inv = 1.0f / (z + 1e-6f);
      int n = n0 + w * 16 + l4 * 4 + r;
#pragma unroll
      for (int cf = 0; cf < 4; ++cf)
        outp[(size_t)(b * 4096 + n) * 1024 + h * 64 + cf * 16 + l15] = oacc[cf][r] * inv;
    }
  }
}

extern "C" void kernel_launch(void* const* d_in, const int* in_sizes, int n_in,
                              void* d_out, int out_size, void* d_ws, size_t ws_size,
                              hipStream_t stream) {
  const float* x = (const float*)d_in[0];
  const float* Wq = (const float*)d_in[1];
  const float* Wk = (const float*)d_in[2];
  const float* Wv = (const float*)d_in[3];
  const float* omg = (const float*)d_in[4];
  float* outp = (float*)d_out;
  char* ws = (char*)d_ws;

  _Float16* wt = (_Float16*)(ws);                 // 6,291,456
  _Float16* om = (_Float16*)(ws + 6291456);       //    32,768
  ushort_t* qkv = (ushort_t*)(ws + 6324224);      // 67,108,864 (Q|K, stride 2048)
  ushort_t* vT = (ushort_t*)(ws + 73433088);      // 33,554,432
  _Float16* xh = (_Float16*)(ws + 106987520);     // 33,554,432 (dead after gemm)
  float* kvp = (float*)(ws + 106987520);          // 33,554,432 = 8 slices x 4 MB (aliases xh)
  float* kv = (float*)(ws + 140541952);           // 4,194,304
  float* pksum = (float*)(ws + 144736256);        //    65,536
  float* pksump = (float*)(ws + 144801792);       //   524,288 (old kvt region)

  k_wtrans<<<dim3(32, 32, 4), dim3(32, 8), 0, stream>>>(Wq, Wk, Wv, omg, wt, om);
  k_xconv<<<dim3(8192), dim3(256), 0, stream>>>(x, xh);
  k_gemm<<<dim3(768), dim3(512), 0, stream>>>(xh, wt, qkv, vT);
  k_kv<<<dim3(64, 8), dim3(256), 0, stream>>>(qkv, vT, om, kvp, pksump);
  k_red<<<dim3(1040), dim3(256), 0, stream>>>(kvp, pksump, kv, pksum);
  k_out<<<dim3(64, 8), dim3(512), 0, stream>>>(qkv, kv, pksum, om, outp);
}

// Round 13
// 230.304 us; speedup vs baseline: 1.1547x; 1.0129x over previous
//
#include <hip/hip_runtime.h>

// Performer (FAVOR+) attention, MI355X.
// B=4 N=4096 H=16 D=64 DIM=1024 M=256.
// Pipeline (5 launches):
//  k_wtrans:  z0-2: W f32 -> wt[g][n][k] fp16; z3: omega->fp16; z4-11: x->xh fp16
//  k_gemm:    r6 structure (111us/40%): 256x256, BK=32, ring-4 LDS,
//             counted vmcnt(6), 1 barrier/K-tile, setprio, XOR swizzle;
//             Q,K -> qkv fp16 (stride 2048); V -> vT bf16 in-epilogue.
//  k_kv:      gload16-staged kt/vt, 1-chunk prefetch, 1 barrier/chunk
//             (pk is wave-private; norms fused into proj via in-register
//             square-sum + shfl tree + shfl permute l15->l4*4+r);
//             per-split slices kvp/pksump (no atomics).
//  k_red2:    kvt[bh][80][264] bf16 = transpose(sum_s kvp) + pksum row 64 +
//             zero rows 65-79 (writes into dead wt region).
//  k_out:     kvl staged by gload16 DMA (overlaps stageQ(0)); norms fused;
//             out = (pq@kv)/(pq@pksum + 1e-6).

typedef _Float16 half8 __attribute__((ext_vector_type(8)));
typedef short short8 __attribute__((ext_vector_type(8)));
typedef float f32x4 __attribute__((ext_vector_type(4)));
typedef unsigned short ushort4v __attribute__((ext_vector_type(4)));
typedef unsigned short ushort_t;
typedef unsigned int uint_t;

#define QKV_LD 2048
#define KVT_ROW 264
#define KVT_SZ 21120  // 80*264 elems per bh

__device__ __forceinline__ ushort_t f2bf(float f) {
  uint_t u = __builtin_bit_cast(uint_t, f);
  u += 0x7fffu + ((u >> 16) & 1u);
  return (ushort_t)(u >> 16);
}

__device__ __forceinline__ void gload16(const void* g, void* l) {
  __builtin_amdgcn_global_load_lds(
      (const __attribute__((address_space(1))) void*)g,
      (__attribute__((address_space(3))) void*)l, 16, 0, 0);
}

#define ENTRY_BAR                                                  \
  asm volatile("s_waitcnt vmcnt(0) lgkmcnt(0)" ::: "memory");      \
  asm volatile("s_barrier" ::: "memory")
#define MID_BAR                                                    \
  asm volatile("s_waitcnt lgkmcnt(0)" ::: "memory");               \
  asm volatile("s_barrier" ::: "memory")

// ---------------- W transpose + omega convert + x convert (one launch) ----------------
__global__ void k_wtrans(const float* __restrict__ Wq, const float* __restrict__ Wk,
                         const float* __restrict__ Wv, const float* __restrict__ omega,
                         const float* __restrict__ x, _Float16* __restrict__ wt,
                         _Float16* __restrict__ om, _Float16* __restrict__ xh) {
  const int g = blockIdx.z;
  const int tx = threadIdx.x, ty = threadIdx.y;
  if (g >= 4) {
    size_t base = (((size_t)(g - 4) * 1024 + blockIdx.y * 32 + blockIdx.x) * 256 +
                   ty * 32 + tx) * 8;
    float4 f0 = *(const float4*)(x + base);
    float4 f1 = *(const float4*)(x + base + 4);
    half8 h;
    h[0] = (_Float16)f0.x; h[1] = (_Float16)f0.y; h[2] = (_Float16)f0.z; h[3] = (_Float16)f0.w;
    h[4] = (_Float16)f1.x; h[5] = (_Float16)f1.y; h[6] = (_Float16)f1.z; h[7] = (_Float16)f1.w;
    *(half8*)(xh + base) = h;
    return;
  }
  if (g == 3) {
    int idx = blockIdx.y * 32 + blockIdx.x;
    if (idx < 64) {
      int i = idx * 256 + ty * 32 + tx;
      om[i] = (_Float16)omega[i];
    }
    return;
  }
  __shared__ float t[32][33];
  const float* W = (g == 0) ? Wq : ((g == 1) ? Wk : Wv);
  const int n0 = blockIdx.x * 32, k0 = blockIdx.y * 32;
#pragma unroll
  for (int j = 0; j < 4; ++j)
    t[ty + j * 8][tx] = W[(size_t)(k0 + ty + j * 8) * 1024 + n0 + tx];
  __syncthreads();
  _Float16* o = wt + (size_t)g * 1024 * 1024;
#pragma unroll
  for (int j = 0; j < 4; ++j)
    o[(size_t)(n0 + ty + j * 8) * 1024 + k0 + tx] = (_Float16)t[tx][ty + j * 8];
}

// ---------------- QKV GEMM: r6 structure (256x256, BK=32, ring-4, 1 bar/K-tile) ----------------
__global__ __launch_bounds__(512, 2) void k_gemm(const _Float16* __restrict__ xh,
                                                 const _Float16* __restrict__ wt,
                                                 ushort_t* __restrict__ qkv,
                                                 ushort_t* __restrict__ vT) {
  __shared__ _Float16 As[4][8192];  // 64 KB; T (36 KB) aliases As in epilogue
  __shared__ _Float16 Bs[4][8192];  // 64 KB
  const int vb = (blockIdx.x & 7) * 96 + (blockIdx.x >> 3);
  const int ct = vb % 12, rt = vb / 12;
  const int col0 = ct * 256, row0 = rt * 256;
  const int g = col0 >> 10;  // 0=Q 1=K 2=V
  const int col0g = col0 & 1023;
  const _Float16* wtg = wt + (size_t)g * (1024 * 1024);
  const int tid = threadIdx.x;
  const int lane = tid & 63;
  const int w = tid >> 6;
  const int wm = w >> 2, wn = w & 3;
  const int l15 = lane & 15, l4 = lane >> 4;

  int srow[2], scol[2], dst[2];
#pragma unroll
  for (int i = 0; i < 2; ++i) {
    int u = i * 512 + tid;
    int rb = u >> 6, rr = (u >> 2) & 15, ccb = u & 3;
    srow[i] = rb * 16 + rr;
    scol[i] = (ccb * 8) ^ ((rr & 8) ? 16 : 0);
    dst[i] = u * 8;
  }
  const int kx = (l4 * 8) ^ ((l15 & 8) ? 16 : 0);

  auto stageA = [&](int b, int kt) {
#pragma unroll
    for (int i = 0; i < 2; ++i)
      gload16(xh + (size_t)(row0 + srow[i]) * 1024 + kt * 32 + scol[i], &As[b][dst[i]]);
  };
  auto stageB = [&](int b, int kt) {
#pragma unroll
    for (int i = 0; i < 2; ++i)
      gload16(wtg + (size_t)(col0g + srow[i]) * 1024 + kt * 32 + scol[i], &Bs[b][dst[i]]);
  };

  f32x4 acc[8][4] = {};

  stageA(0, 0); stageB(0, 0);
  stageA(1, 1); stageB(1, 1);

  for (int kt = 0; kt < 32; ++kt) {
    const int b = kt & 3, b2 = (kt + 2) & 3;
    if (kt < 30) stageA(b2, kt + 2);
    if (kt < 30)       asm volatile("s_waitcnt vmcnt(6)" ::: "memory");
    else if (kt == 30) asm volatile("s_waitcnt vmcnt(4)" ::: "memory");
    else               asm volatile("s_waitcnt vmcnt(0)" ::: "memory");
    asm volatile("s_barrier" ::: "memory");

    const _Float16* Ab = &As[b][0];
    const _Float16* Bb = &Bs[b][0];
    half8 av[4], bv[4];
#pragma unroll
    for (int mi = 0; mi < 4; ++mi)
      av[mi] = *(const half8*)&Ab[(wm * 8 + mi) * 512 + l15 * 32 + kx];
#pragma unroll
    for (int ni = 0; ni < 4; ++ni)
      bv[ni] = *(const half8*)&Bb[(wn * 4 + ni) * 512 + l15 * 32 + kx];
    if (kt < 30) stageB(b2, kt + 2);
    __builtin_amdgcn_s_setprio(1);
#pragma unroll
    for (int mi = 0; mi < 4; ++mi)
#pragma unroll
      for (int ni = 0; ni < 4; ++ni)
        acc[mi][ni] = __builtin_amdgcn_mfma_f32_16x16x32_f16(av[mi], bv[ni], acc[mi][ni], 0, 0, 0);
    __builtin_amdgcn_s_setprio(0);

    half8 av2[4];
#pragma unroll
    for (int mi = 0; mi < 4; ++mi)
      av2[mi] = *(const half8*)&Ab[(wm * 8 + 4 + mi) * 512 + l15 * 32 + kx];
    __builtin_amdgcn_s_setprio(1);
#pragma unroll
    for (int mi = 0; mi < 4; ++mi)
#pragma unroll
      for (int ni = 0; ni < 4; ++ni)
        acc[4 + mi][ni] = __builtin_amdgcn_mfma_f32_16x16x32_f16(av2[mi], bv[ni], acc[4 + mi][ni], 0, 0, 0);
    __builtin_amdgcn_s_setprio(0);
  }

  if (g < 2) {
#pragma unroll
    for (int mi = 0; mi < 8; ++mi) {
      int gr0 = row0 + wm * 128 + mi * 16 + l4 * 4;
#pragma unroll
      for (int ni = 0; ni < 4; ++ni) {
        int gc = col0 + wn * 64 + ni * 16 + l15;
#pragma unroll
        for (int r = 0; r < 4; ++r)
          qkv[(size_t)(gr0 + r) * QKV_LD + gc] =
              __builtin_bit_cast(ushort_t, (_Float16)acc[mi][ni][r]);
      }
    }
  } else {
    ushort_t(*T)[72] = reinterpret_cast<ushort_t(*)[72]>(&As[0][0]);
    const int b_ = row0 >> 12;
    const int n0_ = row0 & 4095;
#pragma unroll
    for (int p = 0; p < 4; ++p) {
      __syncthreads();
      if (wm == (p >> 1)) {
        const int mi0 = (p & 1) * 4;
#pragma unroll
        for (int mi4 = 0; mi4 < 4; ++mi4) {
#pragma unroll
          for (int ni = 0; ni < 4; ++ni) {
            int c = wn * 64 + ni * 16 + l15;
            ushort4v tv;
#pragma unroll
            for (int r = 0; r < 4; ++r) tv[r] = f2bf(acc[mi0 + mi4][ni][r]);
            *(ushort4v*)&T[c][mi4 * 16 + l4 * 4] = tv;
          }
        }
      }
      __syncthreads();
#pragma unroll
      for (int i = 0; i < 4; ++i) {
        int u = i * 512 + tid;
        int c = u >> 3, nc = (u & 7) * 8;
        int h = (col0g + c) >> 6, d = c & 63;
        short8 v = *(const short8*)&T[c][nc];
        *(short8*)(vT + ((size_t)((b_ * 16 + h) * 64 + d)) * 4096 + n0_ + p * 64 + nc) = v;
      }
    }
  }
}

// ---------------- fused phi(k) + kv: 1 barrier/chunk, fused norms, no atomics ----------------
__global__ __launch_bounds__(256) void k_kv(const ushort_t* __restrict__ qkv,
                                            const ushort_t* __restrict__ vT,
                                            const _Float16* __restrict__ om,
                                            float* __restrict__ kvp,
                                            float* __restrict__ pksump) {
  __shared__ _Float16 kt2[2][4096];  // 8 KB each
  __shared__ ushort_t vt2[2][4096];
  __shared__ ushort_t pk[256][72];   // [m][n], wave-private per m-range
  const int bh = blockIdx.x, split = blockIdx.y;
  const int b = bh >> 4, h = bh & 15;
  const int tid = threadIdx.x, lane = tid & 63, w = tid >> 6;
  const int l15 = lane & 15, l4 = lane >> 4;

  int srow[2], scol[2], sdst[2];
#pragma unroll
  for (int i = 0; i < 2; ++i) {
    int u = i * 256 + tid;
    srow[i] = u >> 3;
    scol[i] = ((u & 7) ^ (srow[i] & 7)) * 8;
    sdst[i] = u * 8;
  }
  auto stage = [&](int buf, int c) {
    const int nbase = split * 512 + c * 64;
#pragma unroll
    for (int i = 0; i < 2; ++i) {
      gload16(qkv + (size_t)(b * 4096 + nbase + srow[i]) * QKV_LD + 1024 + h * 64 + scol[i],
              &kt2[buf][sdst[i]]);
      gload16(vT + (size_t)(bh * 64 + srow[i]) * 4096 + nbase + scol[i], &vt2[buf][sdst[i]]);
    }
  };

  half8 bom[4][2];
#pragma unroll
  for (int mf = 0; mf < 4; ++mf)
#pragma unroll
    for (int ks = 0; ks < 2; ++ks)
      bom[mf][ks] = *(const half8*)(om + (size_t)(w * 64 + mf * 16 + l15) * 64 + ks * 32 + l4 * 8);

  f32x4 kvacc[4][4] = {};
  float psum[4] = {0.f, 0.f, 0.f, 0.f};

  stage(0, 0);
#pragma unroll 1
  for (int c = 0; c < 8; ++c) {
    const int cb = c & 1;
    ENTRY_BAR;  // stage(c) landed + cross-wave kt2/vt2 visible; WAR for pk
    if (c < 7) stage(cb ^ 1, c + 1);
    // proj with fused norms: pk[m][n] = bf16(exp(k.om^T - |k|^2/2)/16)
#pragma unroll
    for (int nf = 0; nf < 4; ++nf) {
      int arow = nf * 16 + l15;
      const _Float16* base = &kt2[cb][arow * 64];
      half8 a0 = *(const half8*)&base[(l4 ^ (arow & 7)) * 8];
      half8 a1 = *(const half8*)&base[((4 + l4) ^ (arow & 7)) * 8];
      float pn = 0.f;
#pragma unroll
      for (int e = 0; e < 8; ++e) {
        float u0 = (float)a0[e], u1 = (float)a1[e];
        pn += u0 * u0 + u1 * u1;
      }
      pn += __shfl_xor(pn, 16);
      pn += __shfl_xor(pn, 32);  // |k-row(arow)|^2 in every l4-lane
      float nrr[4];
#pragma unroll
      for (int r = 0; r < 4; ++r) nrr[r] = __shfl(pn, l4 * 4 + r);  // norm of output row
#pragma unroll
      for (int mf = 0; mf < 4; ++mf) {
        f32x4 f = {};
        f = __builtin_amdgcn_mfma_f32_16x16x32_f16(a0, bom[mf][0], f, 0, 0, 0);
        f = __builtin_amdgcn_mfma_f32_16x16x32_f16(a1, bom[mf][1], f, 0, 0, 0);
        ushort4v pw;
#pragma unroll
        for (int r = 0; r < 4; ++r) {
          float p = __expf(f[r] - 0.5f * nrr[r]) * 0.0625f;
          psum[mf] += p;
          pw[r] = f2bf(p);
        }
        *(ushort4v*)&pk[w * 64 + mf * 16 + l15][nf * 16 + l4 * 4] = pw;
      }
    }
    // kv accumulation (pk wave-private: compiler-ordered lgkmcnt, no barrier)
#pragma unroll
    for (int ks = 0; ks < 2; ++ks) {
      short8 pa[4];
#pragma unroll
      for (int mf = 0; mf < 4; ++mf)
        pa[mf] = *(const short8*)&pk[w * 64 + mf * 16 + l15][ks * 32 + l4 * 8];
#pragma unroll
      for (int df = 0; df < 4; ++df) {
        int vrow = df * 16 + l15;
        short8 bv = *(const short8*)&vt2[cb][vrow * 64 + ((4 * ks + l4) ^ (vrow & 7)) * 8];
#pragma unroll
        for (int mf = 0; mf < 4; ++mf)
          kvacc[mf][df] = __builtin_amdgcn_mfma_f32_16x16x32_bf16(pa[mf], bv, kvacc[mf][df], 0, 0, 0);
      }
    }
  }
  float* slice = kvp + (size_t)(split * 64 + bh) * 16384;
#pragma unroll
  for (int mf = 0; mf < 4; ++mf)
#pragma unroll
    for (int df = 0; df < 4; ++df)
#pragma unroll
      for (int r = 0; r < 4; ++r) {
        int m = w * 64 + mf * 16 + l4 * 4 + r;
        int d = df * 16 + l15;
        slice[m * 64 + d] = kvacc[mf][df][r];
      }
#pragma unroll
  for (int mf = 0; mf < 4; ++mf) {
    float v = psum[mf];
    v += __shfl_xor(v, 16);
    v += __shfl_xor(v, 32);
    if (lane < 16)
      pksump[(size_t)(split * 64 + bh) * 256 + w * 64 + mf * 16 + lane] = v;
  }
}

// ---------------- reduce + transpose: kvt[bh][80][264] bf16 ----------------
// grid (64 bh, 4 d-quarters). rows 0..63 = kv^T, row 64 = pksum, 65..79 = 0.
__global__ __launch_bounds__(256) void k_red2(const float* __restrict__ kvp,
                                              const float* __restrict__ pksump,
                                              ushort_t* __restrict__ kvt) {
  __shared__ float kl[256][17];  // [m][d-quarter 16 +1 pad]
  const int bh = blockIdx.x, jq = blockIdx.y, tid = threadIdx.x;
  const int d0 = jq * 16;
#pragma unroll
  for (int i = 0; i < 4; ++i) {
    int u = i * 256 + tid;  // 1024 f32x4 units: m x 4 slots
    int m = u >> 2, s = u & 3;
    f32x4 a = {};
#pragma unroll
    for (int sp = 0; sp < 8; ++sp)
      a += *(const f32x4*)(kvp + (size_t)(sp * 64 + bh) * 16384 + m * 64 + d0 + s * 4);
    *(f32x4*)&kl[m][s * 4] = a;
  }
  __syncthreads();
  const int mg = tid >> 4, jl = tid & 15;
  ushort_t* dstr = kvt + (size_t)bh * KVT_SZ + (d0 + jl) * KVT_ROW + mg * 16;
#pragma unroll
  for (int gpk = 0; gpk < 2; ++gpk) {
    short8 pack;
#pragma unroll
    for (int e = 0; e < 8; ++e)
      pack[e] = (short)f2bf(kl[mg * 16 + gpk * 8 + e][jl]);
    *(short8*)&dstr[gpk * 8] = pack;
  }
  if (jq == 0) {
    float s = 0.f;
#pragma unroll
    for (int sp = 0; sp < 8; ++sp) s += pksump[(size_t)(sp * 64 + bh) * 256 + tid];
    kvt[(size_t)bh * KVT_SZ + 64 * KVT_ROW + tid] = f2bf(s);
  }
  for (int idx = jq * 256 + tid; idx < 15 * KVT_ROW; idx += 1024)
    kvt[(size_t)bh * KVT_SZ + 65 * KVT_ROW + idx] = 0;
}

// ---------------- fused phi(q) + out: DMA-staged kvl, fused norms ----------------
__global__ __launch_bounds__(512) void k_out(const ushort_t* __restrict__ qkv,
                                             const ushort_t* __restrict__ kvt,
                                             const _Float16* __restrict__ om,
                                             float* __restrict__ outp) {
  __shared__ ushort_t kvl[80][KVT_ROW];  // 42.24 KB, layout == kvt
  __shared__ _Float16 qt2[2][8192];      // 16 KB each
  __shared__ ushort_t pq[128][264];      // pq^T [n][m]
  const int bh = blockIdx.x, ns = blockIdx.y;
  const int b = bh >> 4, h = bh & 15;
  const int tid = threadIdx.x, lane = tid & 63, w = tid >> 6;
  const int l15 = lane & 15, l4 = lane >> 4;
  const int wn = w >> 2, wm = w & 3;

  // kvl DMA (linear 1:1 copy of kvt tile) + q chunk0, both in flight together
  {
    const ushort_t* kvsrc = kvt + (size_t)bh * KVT_SZ;
    ushort_t* dstl = &kvl[0][0];
#pragma unroll
    for (int i = 0; i < 6; ++i) {
      int u = i * 512 + tid;
      if (u < 2640) gload16(kvsrc + u * 8, dstl + u * 8);
    }
  }
  int srow[2], scol[2], sdst[2];
#pragma unroll
  for (int i = 0; i < 2; ++i) {
    int u = i * 512 + tid;
    srow[i] = u >> 3;
    scol[i] = ((u & 7) ^ (srow[i] & 7)) * 8;
    sdst[i] = u * 8;
  }
  auto stageQ = [&](int buf, int ch) {
    const int n0 = ns * 512 + ch * 128;
#pragma unroll
    for (int i = 0; i < 2; ++i)
      gload16((const _Float16*)qkv + (size_t)(b * 4096 + n0 + srow[i]) * QKV_LD + h * 64 + scol[i],
              &qt2[buf][sdst[i]]);
  };
  stageQ(0, 0);

  half8 bom[4][2];
#pragma unroll
  for (int mf = 0; mf < 4; ++mf)
#pragma unroll
    for (int ks = 0; ks < 2; ++ks)
      bom[mf][ks] = *(const half8*)(om + (size_t)(wm * 64 + mf * 16 + l15) * 64 + ks * 32 + l4 * 8);

#pragma unroll 1
  for (int ch = 0; ch < 4; ++ch) {
    const int cb = ch & 1;
    const int n0 = ns * 512 + ch * 128;
    ENTRY_BAR;  // drains stageQ(ch) (+kvl on ch0); WAR for pq
    if (ch < 3) stageQ(cb ^ 1, ch + 1);
    // swapped proj with fused norms (output col == loaded q-row -> no permute)
#pragma unroll
    for (int nf = 0; nf < 4; ++nf) {
      int arow = wn * 64 + nf * 16 + l15;
      const _Float16* base = &qt2[cb][arow * 64];
      half8 qa0 = *(const half8*)&base[(l4 ^ (arow & 7)) * 8];
      half8 qa1 = *(const half8*)&base[((4 + l4) ^ (arow & 7)) * 8];
      float pn = 0.f;
#pragma unroll
      for (int e = 0; e < 8; ++e) {
        float u0 = (float)qa0[e], u1 = (float)qa1[e];
        pn += u0 * u0 + u1 * u1;
      }
      pn += __shfl_xor(pn, 16);
      pn += __shfl_xor(pn, 32);
      float nr = 0.5f * pn;
#pragma unroll
      for (int mf = 0; mf < 4; ++mf) {
        f32x4 f = {};
        f = __builtin_amdgcn_mfma_f32_16x16x32_f16(bom[mf][0], qa0, f, 0, 0, 0);
        f = __builtin_amdgcn_mfma_f32_16x16x32_f16(bom[mf][1], qa1, f, 0, 0, 0);
        ushort4v pw;
#pragma unroll
        for (int r = 0; r < 4; ++r) {
          float p = __expf(f[r] - nr) * 0.0625f;
          pw[r] = f2bf(p);
        }
        *(ushort4v*)&pq[wn * 64 + nf * 16 + l15][wm * 64 + mf * 16 + l4 * 4] = pw;
      }
    }
    MID_BAR;  // pq is cross-wave (4 wm waves fill each row)
    f32x4 oacc[5] = {};
#pragma unroll
    for (int ks = 0; ks < 8; ++ks) {
      short8 pa = *(const short8*)&pq[w * 16 + l15][ks * 32 + l4 * 8];
#pragma unroll
      for (int cf = 0; cf < 5; ++cf) {
        short8 bv = *(const short8*)&kvl[cf * 16 + l15][ks * 32 + l4 * 8];
        oacc[cf] = __builtin_amdgcn_mfma_f32_16x16x32_bf16(pa, bv, oacc[cf], 0, 0, 0);
      }
    }
#pragma unroll
    for (int r = 0; r < 4; ++r) {
      float z = __shfl(oacc[4][r], lane & 48);
      float inv = 1.0f / (z + 1e-6f);
      int n = n0 + w * 16 + l4 * 4 + r;
#pragma unroll
      for (int cf = 0; cf < 4; ++cf)
        outp[(size_t)(b * 4096 + n) * 1024 + h * 64 + cf * 16 + l15] = oacc[cf][r] * inv;
    }
  }
}

extern "C" void kernel_launch(void* const* d_in, const int* in_sizes, int n_in,
                              void* d_out, int out_size, void* d_ws, size_t ws_size,
                              hipStream_t stream) {
  const float* x = (const float*)d_in[0];
  const float* Wq = (const float*)d_in[1];
  const float* Wk = (const float*)d_in[2];
  const float* Wv = (const float*)d_in[3];
  const float* omg = (const float*)d_in[4];
  float* outp = (float*)d_out;
  char* ws = (char*)d_ws;

  _Float16* wt = (_Float16*)(ws);                 // 6,291,456 (dead after gemm)
  ushort_t* kvt = (ushort_t*)(ws);                // 2,703,360 (aliases wt)
  _Float16* om = (_Float16*)(ws + 6291456);       //    32,768
  ushort_t* qkv = (ushort_t*)(ws + 6324224);      // 67,108,864 (Q|K, stride 2048)
  ushort_t* vT = (ushort_t*)(ws + 73433088);      // 33,554,432
  _Float16* xh = (_Float16*)(ws + 106987520);     // 33,554,432 (dead after gemm)
  float* kvp = (float*)(ws + 106987520);          // 33,554,432 (aliases xh)
  float* pksump = (float*)(ws + 140541952);       //    524,288

  k_wtrans<<<dim3(32, 32, 12), dim3(32, 8), 0, stream>>>(Wq, Wk, Wv, omg, x, wt, om, xh);
  k_gemm<<<dim3(768), dim3(512), 0, stream>>>(xh, wt, qkv, vT);
  k_kv<<<dim3(64, 8), dim3(256), 0, stream>>>(qkv, vT, om, kvp, pksump);
  k_red2<<<dim3(64, 4), dim3(256), 0, stream>>>(kvp, pksump, kvt);
  k_out<<<dim3(64, 8), dim3(512), 0, stream>>>(qkv, kvt, om, outp);
}